// Round 4
// baseline (1386.912 us; speedup 1.0000x reference)
//
#include <hip/hip_runtime.h>
#include <hip/hip_bf16.h>
#include <math.h>

#define NTOK 8192      // B*T = 4*2048
#define DDIM 1024
#define HDIM 4096
#define NEXP 8
#define HROWS (NTOK*2 + 256)   // compact pair rows + pad for ragged 256-tile overread
#define RBLK 512               // route blocks (16 tokens each)

typedef unsigned int u32;
typedef unsigned short u16;
typedef __bf16 bf16x8 __attribute__((ext_vector_type(8)));
typedef float f32x4 __attribute__((ext_vector_type(4)));
typedef u16 u16x8 __attribute__((ext_vector_type(8)));
typedef u16 u16x4 __attribute__((ext_vector_type(4)));

#define SCHEDB __builtin_amdgcn_sched_barrier(0)
#define BARR   __builtin_amdgcn_s_barrier()
#define LGKM0  asm volatile("s_waitcnt lgkmcnt(0)" ::: "memory")
#define VMC8   asm volatile("s_waitcnt vmcnt(8)" ::: "memory")
#define VMC0   asm volatile("s_waitcnt vmcnt(0)" ::: "memory")

__device__ __forceinline__ u16 f2bf(float f){
  u32 u = __builtin_bit_cast(u32, f);
  u32 r = (u + 0x7FFFu + ((u >> 16) & 1u)) >> 16;   // RNE
  return (u16)r;
}
__device__ __forceinline__ float bf2f(u16 b){
  u32 u = ((u32)b) << 16;
  return __builtin_bit_cast(float, u);
}
__device__ __forceinline__ void gl_lds16(const void* g, void* l){
  __builtin_amdgcn_global_load_lds(
      (const __attribute__((address_space(1))) u32*)g,
      (__attribute__((address_space(3))) u32*)l, 16, 0, 0);
}
// swizzled LDS fragment read: row r (includes fr), k-step kk, quarter fq
__device__ __forceinline__ bf16x8 ldsrd(const u16* base, int r, int kk, int fq, int fr){
  int chunk = (kk * 4 + fq) ^ (fr & 7);
  return *(const bf16x8*)&base[r * 64 + chunk * 8];
}

// ---------------- convert x fp32 -> bf16 ----------------
__global__ __launch_bounds__(256) void cvtx_kernel(const float* __restrict__ x,
                                                   u16* __restrict__ xb){
  long i = (long)(blockIdx.x * 256 + threadIdx.x) * 8;
  float4 a = *(const float4*)(x + i);
  float4 b = *(const float4*)(x + i + 4);
  u16x8 o;
  o[0]=f2bf(a.x); o[1]=f2bf(a.y); o[2]=f2bf(a.z); o[3]=f2bf(a.w);
  o[4]=f2bf(b.x); o[5]=f2bf(b.y); o[6]=f2bf(b.z); o[7]=f2bf(b.w);
  *(u16x8*)(xb + i) = o;
}

// ------------- transpose+convert: in [R][C] fp32 -> out [C][R] bf16, per expert -------------
__global__ __launch_bounds__(256) void transpose_cvt(const float* __restrict__ in,
                                                     u16* __restrict__ out,
                                                     int R, int C){
  int e = blockIdx.z;
  const float* pin = in + (long)e * R * C;
  u16* pout = out + (long)e * R * C;
  __shared__ u16 tile[64][65];
  int c0 = blockIdx.x * 64, r0 = blockIdx.y * 64;
  int tid = threadIdx.x;
#pragma unroll
  for (int j = 0; j < 16; j++){
    int idx = tid + 256 * j;
    int r = idx >> 6, c = idx & 63;
    tile[r][c] = f2bf(pin[(long)(r0 + r) * C + c0 + c]);
  }
  __syncthreads();
#pragma unroll
  for (int j = 0; j < 16; j++){
    int idx = tid + 256 * j;
    int r = idx >> 6, c = idx & 63;
    pout[(long)(c0 + r) * R + r0 + c] = tile[c][r];
  }
}

// ---------------- routing phase 1: 1 wave per token, no global atomics ----------------
__global__ __launch_bounds__(1024) void route_kernel(const float* __restrict__ x,
                                                     const float* __restrict__ Wr,
                                                     int4* __restrict__ meta,
                                                     float2* __restrict__ gates,
                                                     int* __restrict__ selrk,
                                                     int* __restrict__ blockhist,
                                                     float* __restrict__ impPart){
  const int wid = threadIdx.x >> 6;       // 0..15 (token within block)
  const int lane = threadIdx.x & 63;
  const int t = blockIdx.x * 16 + wid;
  const float* xr = x + (long)t * DDIM;
  float acc[NEXP] = {};
  for (int d0 = lane * 4; d0 < DDIM; d0 += 256){
    float4 xv = *(const float4*)(xr + d0);
    const float* w = Wr + d0 * NEXP;
#pragma unroll
    for (int q = 0; q < 4; q++){
      float xq = ((const float*)&xv)[q];
      float4 w0 = *(const float4*)(w + q * NEXP);
      float4 w1 = *(const float4*)(w + q * NEXP + 4);
      acc[0] += xq * w0.x; acc[1] += xq * w0.y; acc[2] += xq * w0.z; acc[3] += xq * w0.w;
      acc[4] += xq * w1.x; acc[5] += xq * w1.y; acc[6] += xq * w1.z; acc[7] += xq * w1.w;
    }
  }
#pragma unroll
  for (int e = 0; e < NEXP; e++){
#pragma unroll
    for (int off = 32; off; off >>= 1) acc[e] += __shfl_xor(acc[e], off, 64);
  }
  __shared__ int sel_s[32];
  __shared__ float p_s[16][NEXP];
  if (lane == 0){
    float mx = acc[0];
#pragma unroll
    for (int e = 1; e < NEXP; e++) mx = fmaxf(mx, acc[e]);
    float p[NEXP]; float s = 0.f;
#pragma unroll
    for (int e = 0; e < NEXP; e++){ p[e] = expf(acc[e] - mx); s += p[e]; }
    float inv = 1.f / s;
#pragma unroll
    for (int e = 0; e < NEXP; e++){ p[e] *= inv; p_s[wid][e] = p[e]; }
    int i0 = 0; float v0 = p[0];
#pragma unroll
    for (int e = 1; e < NEXP; e++) if (p[e] > v0){ v0 = p[e]; i0 = e; }
    int i1 = -1; float v1 = -1.f;
#pragma unroll
    for (int e = 0; e < NEXP; e++) if (e != i0 && p[e] > v1){ v1 = p[e]; i1 = e; }
    float gs = v0 + v1 + 1e-9f;
    meta[t] = make_int4(i0, i1, 0, 0);
    gates[t] = make_float2(v0 / gs, v1 / gs);
    sel_s[wid * 2] = i0;
    sel_s[wid * 2 + 1] = i1;
  }
  __syncthreads();
  const int tid = threadIdx.x;
  if (tid < 32){
    int e = sel_s[tid];
    int r = 0;
    for (int m = 0; m < tid; m++) r += (sel_s[m] == e) ? 1 : 0;
    selrk[blockIdx.x * 32 + tid] = (r << 3) | e;
  }
  if (tid < NEXP){
    int hcount = 0;
#pragma unroll
    for (int m = 0; m < 32; m++) hcount += (sel_s[m] == tid) ? 1 : 0;
    blockhist[blockIdx.x * NEXP + tid] = hcount;
    float s = 0.f;
#pragma unroll
    for (int w = 0; w < 16; w++) s += p_s[w][tid];
    impPart[blockIdx.x * NEXP + tid] = s;
  }
}

// ---------------- routing phase 2: exclusive scan of block histograms ----------------
__global__ __launch_bounds__(512) void scan_kernel(int* __restrict__ blockhist,
                                                   const float* __restrict__ impPart,
                                                   int* __restrict__ cnt,
                                                   int* __restrict__ offs,
                                                   float* __restrict__ imp){
  const int e = threadIdx.x >> 6;     // expert 0..7
  const int lane = threadIdx.x & 63;
  const int base = lane * 8;          // 8 blocks per lane, 512 total
  int v[8]; int s = 0;
#pragma unroll
  for (int i = 0; i < 8; i++){
    int tmp = blockhist[(base + i) * NEXP + e];
    v[i] = s; s += tmp;
  }
  int inc = s;
#pragma unroll
  for (int off = 1; off < 64; off <<= 1){
    int o = __shfl_up(inc, off, 64);
    if (lane >= off) inc += o;
  }
  int excl = inc - s;
#pragma unroll
  for (int i = 0; i < 8; i++) blockhist[(base + i) * NEXP + e] = v[i] + excl;
  int tot = __shfl(inc, 63, 64);
  float fs = 0.f;
#pragma unroll
  for (int i = 0; i < 8; i++) fs += impPart[(base + i) * NEXP + e];
#pragma unroll
  for (int off = 32; off; off >>= 1) fs += __shfl_xor(fs, off, 64);
  __shared__ int cnt_s[NEXP];
  if (lane == 0){ cnt_s[e] = tot; cnt[e] = tot; imp[e] = fs; }
  __syncthreads();
  if (threadIdx.x == 0){
    int o = 0;
    for (int q = 0; q < NEXP; q++){ offs[q] = o; o += cnt_s[q]; }
  }
}

// ---------------- routing phase 3: write compact expert lists + slots ----------------
__global__ __launch_bounds__(256) void fill_kernel(const int* __restrict__ selrk,
                                                   const int* __restrict__ blockhist,
                                                   int* __restrict__ elist,
                                                   int4* __restrict__ meta){
  int m = blockIdx.x * 256 + threadIdx.x;   // assignment index, 0..2*NTOK-1
  int t = m >> 1, c = m & 1, b = m >> 5;
  int pk = selrk[m];
  int e = pk & 7, r = pk >> 3;
  int gslot = blockhist[b * NEXP + e] + r;
  elist[e * NTOK + gslot] = t;
  ((int*)meta)[t * 4 + 2 + c] = gslot;
}

// ---------------- 8-phase 256x256 GEMM (BK=64, 8 waves, counted vmcnt) ----------------
// C[compact rows] = act(A_rows @ Bt[e]); A gathered (gemm1) or compact h (gemm2).
template<int KD, int ND, bool GATHER, bool GELU>
__global__ __launch_bounds__(512) void gemm8p_kernel(const u16* __restrict__ Ag,
                                                     const u16* __restrict__ Bg,
                                                     u16* __restrict__ Cg,
                                                     const int* __restrict__ elist,
                                                     const int* __restrict__ cnt,
                                                     const int* __restrict__ offs){
  const int NBT = ND / 256;
  const int nloc = 32 * NBT;
  const int e  = blockIdx.x / nloc;
  const int rr = blockIdx.x % nloc;
  const int nb = rr / 32;        // consecutive blocks share the B panel (tt inner)
  const int tt = rr % 32;
  const int n_e = cnt[e];
  if (tt * 256 >= n_e) return;

  __shared__ __align__(16) u16 As[2][256 * 64];
  __shared__ __align__(16) u16 Bs[2][256 * 64];

  const int tid = threadIdx.x;
  const int w = tid >> 6, l = tid & 63;
  const int wm = w >> 2, wn = w & 3;           // 2 x 4 wave grid
  const int wrow = wm * 128, wcol = wn * 64;
  const int fr = l & 15, fq = l >> 4;
  const int chunk = (l & 7) ^ ((l >> 3) & 7);  // pre-swizzled global source chunk
  const int row0 = offs[e] + tt * 256;

  // staging addresses: call i covers rows i*64 + w*8 + (l>>3)
  int srcA[4], srcB[4], ldsO[4];
#pragma unroll
  for (int i = 0; i < 4; i++){
    int rowg = i * 64 + w * 8 + (l >> 3);
    int arow;
    if (GATHER){
      int slot = tt * 256 + rowg;
      if (slot >= n_e) slot = n_e - 1;
      arow = elist[e * NTOK + slot];
    } else {
      arow = row0 + rowg;
    }
    srcA[i] = arow * KD + chunk * 8;
    srcB[i] = (e * ND + nb * 256 + rowg) * KD + chunk * 8;
    ldsO[i] = rowg * 64 + (l & 7) * 8;   // == lane0_base + l*16B (linear dest)
  }

  const int NKT = KD / 64;
  f32x4 acc[8][4] = {};

  // prologue: stage tiles 0 and 1
#pragma unroll
  for (int i = 0; i < 4; i++){
    gl_lds16(Ag + srcA[i], &As[0][ldsO[i]]);
    gl_lds16(Bg + srcB[i], &Bs[0][ldsO[i]]);
  }
#pragma unroll
  for (int i = 0; i < 4; i++){
    gl_lds16(Ag + srcA[i] + 64, &As[1][ldsO[i]]);
    gl_lds16(Bg + srcB[i] + 64, &Bs[1][ldsO[i]]);
  }
  SCHEDB; VMC8; SCHEDB; BARR; SCHEDB;   // tile 0 ready everywhere

  for (int t = 0; t < NKT; ++t){
    const int p = t & 1;
    const u16* Ap = &As[p][0];
    const u16* Bp = &Bs[p][0];
    bf16x8 a[4][2], b0[2][2], b1[2][2];
    // ---- P0: A-low + B-low, MFMA quadrant (m 0..3, n 0..1)
#pragma unroll
    for (int m = 0; m < 4; m++)
#pragma unroll
      for (int kk = 0; kk < 2; kk++)
        a[m][kk] = ldsrd(Ap, wrow + m * 16 + fr, kk, fq, fr);
#pragma unroll
    for (int n = 0; n < 2; n++)
#pragma unroll
      for (int kk = 0; kk < 2; kk++)
        b0[n][kk] = ldsrd(Bp, wcol + n * 16 + fr, kk, fq, fr);
    __builtin_amdgcn_s_setprio(1);
#pragma unroll
    for (int kk = 0; kk < 2; kk++)
#pragma unroll
      for (int m = 0; m < 4; m++)
#pragma unroll
        for (int n = 0; n < 2; n++)
          acc[m][n] = __builtin_amdgcn_mfma_f32_16x16x32_bf16(a[m][kk], b0[n][kk], acc[m][n], 0, 0, 0);
    __builtin_amdgcn_s_setprio(0);
    // ---- P1: B-high, quadrant (m 0..3, n 2..3)
#pragma unroll
    for (int n = 0; n < 2; n++)
#pragma unroll
      for (int kk = 0; kk < 2; kk++)
        b1[n][kk] = ldsrd(Bp, wcol + 32 + n * 16 + fr, kk, fq, fr);
    __builtin_amdgcn_s_setprio(1);
#pragma unroll
    for (int kk = 0; kk < 2; kk++)
#pragma unroll
      for (int m = 0; m < 4; m++)
#pragma unroll
        for (int n = 0; n < 2; n++)
          acc[m][2 + n] = __builtin_amdgcn_mfma_f32_16x16x32_bf16(a[m][kk], b1[n][kk], acc[m][2 + n], 0, 0, 0);
    __builtin_amdgcn_s_setprio(0);
    // ---- P2: A-high, quadrant (m 4..7, n 0..1)
#pragma unroll
    for (int m = 0; m < 4; m++)
#pragma unroll
      for (int kk = 0; kk < 2; kk++)
        a[m][kk] = ldsrd(Ap, wrow + 64 + m * 16 + fr, kk, fq, fr);
    __builtin_amdgcn_s_setprio(1);
#pragma unroll
    for (int kk = 0; kk < 2; kk++)
#pragma unroll
      for (int m = 0; m < 4; m++)
#pragma unroll
        for (int n = 0; n < 2; n++)
          acc[4 + m][n] = __builtin_amdgcn_mfma_f32_16x16x32_bf16(a[m][kk], b0[n][kk], acc[4 + m][n], 0, 0, 0);
    __builtin_amdgcn_s_setprio(0);
    // ---- P3: all reads of buf[p] complete -> barrier -> restage buf[p] with tile t+2
    LGKM0; SCHEDB; BARR; SCHEDB;
    if (t + 2 < NKT){
      const int kb = (t + 2) * 64;
#pragma unroll
      for (int i = 0; i < 4; i++){
        gl_lds16(Ag + srcA[i] + kb, &As[p][ldsO[i]]);
        gl_lds16(Bg + srcB[i] + kb, &Bs[p][ldsO[i]]);
      }
    }
    __builtin_amdgcn_s_setprio(1);
#pragma unroll
    for (int kk = 0; kk < 2; kk++)
#pragma unroll
      for (int m = 0; m < 4; m++)
#pragma unroll
        for (int n = 0; n < 2; n++)
          acc[4 + m][2 + n] = __builtin_amdgcn_mfma_f32_16x16x32_bf16(a[m][kk], b1[n][kk], acc[4 + m][2 + n], 0, 0, 0);
    __builtin_amdgcn_s_setprio(0);
    if (t + 1 < NKT){
      SCHEDB;
      if (t + 2 < NKT) { VMC8; } else { VMC0; }   // tile t+1 ready (counted, never drains prefetch)
      SCHEDB; BARR; SCHEDB;
    }
  }

  // epilogue
  const int c0 = nb * 256 + wcol;
#pragma unroll
  for (int m = 0; m < 8; m++){
#pragma unroll
    for (int j = 0; j < 4; j++){
      int slot = tt * 256 + wrow + m * 16 + fq * 4 + j;
      if (slot >= n_e) continue;
      long base = (long)(offs[e] + slot) * ND + c0;
#pragma unroll
      for (int n = 0; n < 4; n++){
        float v = acc[m][n][j];
        if (GELU) v = 0.5f * v * (1.0f + erff(v * 0.70710678118f));
        Cg[base + n * 16 + fr] = f2bf(v);
      }
    }
  }
}

// ---------------- combine: out[t] = g0*y0 + g1*y1 ----------------
__global__ __launch_bounds__(256) void combine_kernel(const u16* __restrict__ ypair,
                                                      const int4* __restrict__ meta,
                                                      const float2* __restrict__ gates,
                                                      const int* __restrict__ offs,
                                                      float* __restrict__ out){
  int t = blockIdx.x;
  int c = threadIdx.x;
  int4 m = meta[t];
  float2 g = gates[t];
  long p0 = (long)(offs[m.x] + m.z) * DDIM + c * 4;
  long p1 = (long)(offs[m.y] + m.w) * DDIM + c * 4;
  u16x4 y0 = *(const u16x4*)&ypair[p0];
  u16x4 y1 = *(const u16x4*)&ypair[p1];
  float4 o;
  o.x = g.x * bf2f(y0[0]) + g.y * bf2f(y1[0]);
  o.y = g.x * bf2f(y0[1]) + g.y * bf2f(y1[1]);
  o.z = g.x * bf2f(y0[2]) + g.y * bf2f(y1[2]);
  o.w = g.x * bf2f(y0[3]) + g.y * bf2f(y1[3]);
  *(float4*)&out[(long)t * DDIM + c * 4] = o;
}

// ---------------- load-balance loss ----------------
__global__ void lb_kernel(const float* __restrict__ imp, const int* __restrict__ cnt,
                          float* __restrict__ outp){
  if (threadIdx.x == 0 && blockIdx.x == 0){
    float si = 0.f, sl = 0.f;
    for (int e = 0; e < NEXP; e++){ si += imp[e]; sl += (float)cnt[e]; }
    float lb = 0.f;
    for (int e = 0; e < NEXP; e++)
      lb += (imp[e] / (si + 1e-9f)) * ((float)cnt[e] / (sl + 1e-9f));
    outp[0] = lb * (float)NEXP;
  }
}

extern "C" void kernel_launch(void* const* d_in, const int* in_sizes, int n_in,
                              void* d_out, int out_size, void* d_ws, size_t ws_size,
                              hipStream_t stream){
  const float* x  = (const float*)d_in[0];
  const float* Wr = (const float*)d_in[1];
  const float* W1 = (const float*)d_in[2];
  const float* W2 = (const float*)d_in[3];
  float* out = (float*)d_out;
  char* ws = (char*)d_ws;
  size_t off = 0;
  u16* xb = (u16*)(ws + off);   off += (size_t)NTOK * DDIM * 2;
  u16* wt = (u16*)(ws + off);   off += (size_t)NEXP * DDIM * HDIM * 2;   // reused: W1^T then W2^T
  u16* h  = (u16*)(ws + off);   off += (size_t)HROWS * HDIM * 2;
  u16* yp = (u16*)(ws + off);   off += (size_t)NTOK * 2 * DDIM * 2;
  int* elist    = (int*)(ws + off);    off += (size_t)NEXP * NTOK * 4;
  int4* meta    = (int4*)(ws + off);   off += (size_t)NTOK * 16;
  float2* gts   = (float2*)(ws + off); off += (size_t)NTOK * 8;
  int* selrk    = (int*)(ws + off);    off += (size_t)NTOK * 2 * 4;
  int* bhist    = (int*)(ws + off);    off += (size_t)RBLK * NEXP * 4;
  float* impP   = (float*)(ws + off);  off += (size_t)RBLK * NEXP * 4;
  int* cnt      = (int*)(ws + off);    off += 32;
  float* imp    = (float*)(ws + off);  off += 32;
  int* offs     = (int*)(ws + off);    off += 32;
  if (ws_size < off) return;  // insufficient workspace: fail visibly

  cvtx_kernel<<<4096, 256, 0, stream>>>(x, xb);
  route_kernel<<<RBLK, 1024, 0, stream>>>(x, Wr, meta, gts, selrk, bhist, impP);
  scan_kernel<<<1, 512, 0, stream>>>(bhist, impP, cnt, offs, imp);
  fill_kernel<<<NTOK * 2 / 256, 256, 0, stream>>>(selrk, bhist, elist, meta);
  transpose_cvt<<<dim3(HDIM / 64, DDIM / 64, NEXP), 256, 0, stream>>>(W1, wt, DDIM, HDIM);
  gemm8p_kernel<DDIM, HDIM, true, true><<<NEXP * 32 * (HDIM / 256), 512, 0, stream>>>(
      xb, wt, h, elist, cnt, offs);
  transpose_cvt<<<dim3(DDIM / 64, HDIM / 64, NEXP), 256, 0, stream>>>(W2, wt, HDIM, DDIM);
  gemm8p_kernel<HDIM, DDIM, false, false><<<NEXP * 32 * (DDIM / 256), 512, 0, stream>>>(
      h, wt, yp, elist, cnt, offs);
  combine_kernel<<<NTOK, 256, 0, stream>>>(yp, meta, gts, offs, out);
  lb_kernel<<<1, 64, 0, stream>>>(imp, cnt, out + (size_t)NTOK * DDIM);
}

// Round 5
// 1360.857 us; speedup vs baseline: 1.0191x; 1.0191x over previous
//
#include <hip/hip_runtime.h>
#include <hip/hip_bf16.h>
#include <math.h>

#define NTOK 8192      // B*T = 4*2048
#define DDIM 1024
#define HDIM 4096
#define NEXP 8
#define HROWS (NTOK*2 + 256)   // compact pair rows + pad for ragged 256-tile overread
#define RBLK 512               // route blocks (16 tokens each)

typedef unsigned int u32;
typedef unsigned short u16;
typedef __bf16 bf16x8 __attribute__((ext_vector_type(8)));
typedef float f32x4 __attribute__((ext_vector_type(4)));
typedef u32 u32x4 __attribute__((ext_vector_type(4)));
typedef u16 u16x8 __attribute__((ext_vector_type(8)));
typedef u16 u16x4 __attribute__((ext_vector_type(4)));

#define SCHEDB __builtin_amdgcn_sched_barrier(0)
#define BARR   __builtin_amdgcn_s_barrier()
#define LGKM0  asm volatile("s_waitcnt lgkmcnt(0)" ::: "memory")
#define VMC8   asm volatile("s_waitcnt vmcnt(8)" ::: "memory")
#define VMC0   asm volatile("s_waitcnt vmcnt(0)" ::: "memory")

__device__ __forceinline__ u16 f2bf(float f){
  u32 u = __builtin_bit_cast(u32, f);
  u32 r = (u + 0x7FFFu + ((u >> 16) & 1u)) >> 16;   // RNE
  return (u16)r;
}
__device__ __forceinline__ float bf2f(u16 b){
  u32 u = ((u32)b) << 16;
  return __builtin_bit_cast(float, u);
}
__device__ __forceinline__ void gl_lds16(const void* g, void* l){
  __builtin_amdgcn_global_load_lds(
      (const __attribute__((address_space(1))) u32*)g,
      (__attribute__((address_space(3))) u32*)l, 16, 0, 0);
}
// inline-asm LDS read: invisible to SIInsertWaitcnts (no conservative vmcnt
// drain vs in-flight global_load_lds). Caller MUST do LGKM0; SCHEDB before use.
__device__ __forceinline__ bf16x8 ldsr(u32 addr){
  u32x4 r;
  asm volatile("ds_read_b128 %0, %1" : "=v"(r) : "v"(addr));
  return __builtin_bit_cast(bf16x8, r);
}

// ---------------- convert x fp32 -> bf16 ----------------
__global__ __launch_bounds__(256) void cvtx_kernel(const float* __restrict__ x,
                                                   u16* __restrict__ xb){
  long i = (long)(blockIdx.x * 256 + threadIdx.x) * 8;
  float4 a = *(const float4*)(x + i);
  float4 b = *(const float4*)(x + i + 4);
  u16x8 o;
  o[0]=f2bf(a.x); o[1]=f2bf(a.y); o[2]=f2bf(a.z); o[3]=f2bf(a.w);
  o[4]=f2bf(b.x); o[5]=f2bf(b.y); o[6]=f2bf(b.z); o[7]=f2bf(b.w);
  *(u16x8*)(xb + i) = o;
}

// ------------- transpose+convert: in [R][C] fp32 -> out [C][R] bf16, per expert -------------
__global__ __launch_bounds__(256) void transpose_cvt(const float* __restrict__ in,
                                                     u16* __restrict__ out,
                                                     int R, int C){
  int e = blockIdx.z;
  const float* pin = in + (long)e * R * C;
  u16* pout = out + (long)e * R * C;
  __shared__ u16 tile[64][65];
  int c0 = blockIdx.x * 64, r0 = blockIdx.y * 64;
  int tid = threadIdx.x;
#pragma unroll
  for (int j = 0; j < 16; j++){
    int idx = tid + 256 * j;
    int r = idx >> 6, c = idx & 63;
    tile[r][c] = f2bf(pin[(long)(r0 + r) * C + c0 + c]);
  }
  __syncthreads();
#pragma unroll
  for (int j = 0; j < 16; j++){
    int idx = tid + 256 * j;
    int r = idx >> 6, c = idx & 63;
    pout[(long)(c0 + r) * R + r0 + c] = tile[c][r];
  }
}

// ---------------- routing phase 1: 1 wave per token, no global atomics ----------------
__global__ __launch_bounds__(1024) void route_kernel(const float* __restrict__ x,
                                                     const float* __restrict__ Wr,
                                                     int4* __restrict__ meta,
                                                     float2* __restrict__ gates,
                                                     int* __restrict__ selrk,
                                                     int* __restrict__ blockhist,
                                                     float* __restrict__ impPart){
  const int wid = threadIdx.x >> 6;       // 0..15 (token within block)
  const int lane = threadIdx.x & 63;
  const int t = blockIdx.x * 16 + wid;
  const float* xr = x + (long)t * DDIM;
  float acc[NEXP] = {};
  for (int d0 = lane * 4; d0 < DDIM; d0 += 256){
    float4 xv = *(const float4*)(xr + d0);
    const float* w = Wr + d0 * NEXP;
#pragma unroll
    for (int q = 0; q < 4; q++){
      float xq = ((const float*)&xv)[q];
      float4 w0 = *(const float4*)(w + q * NEXP);
      float4 w1 = *(const float4*)(w + q * NEXP + 4);
      acc[0] += xq * w0.x; acc[1] += xq * w0.y; acc[2] += xq * w0.z; acc[3] += xq * w0.w;
      acc[4] += xq * w1.x; acc[5] += xq * w1.y; acc[6] += xq * w1.z; acc[7] += xq * w1.w;
    }
  }
#pragma unroll
  for (int e = 0; e < NEXP; e++){
#pragma unroll
    for (int off = 32; off; off >>= 1) acc[e] += __shfl_xor(acc[e], off, 64);
  }
  __shared__ int sel_s[32];
  __shared__ float p_s[16][NEXP];
  if (lane == 0){
    float mx = acc[0];
#pragma unroll
    for (int e = 1; e < NEXP; e++) mx = fmaxf(mx, acc[e]);
    float p[NEXP]; float s = 0.f;
#pragma unroll
    for (int e = 0; e < NEXP; e++){ p[e] = expf(acc[e] - mx); s += p[e]; }
    float inv = 1.f / s;
#pragma unroll
    for (int e = 0; e < NEXP; e++){ p[e] *= inv; p_s[wid][e] = p[e]; }
    int i0 = 0; float v0 = p[0];
#pragma unroll
    for (int e = 1; e < NEXP; e++) if (p[e] > v0){ v0 = p[e]; i0 = e; }
    int i1 = -1; float v1 = -1.f;
#pragma unroll
    for (int e = 0; e < NEXP; e++) if (e != i0 && p[e] > v1){ v1 = p[e]; i1 = e; }
    float gs = v0 + v1 + 1e-9f;
    meta[t] = make_int4(i0, i1, 0, 0);
    gates[t] = make_float2(v0 / gs, v1 / gs);
    sel_s[wid * 2] = i0;
    sel_s[wid * 2 + 1] = i1;
  }
  __syncthreads();
  const int tid = threadIdx.x;
  if (tid < 32){
    int e = sel_s[tid];
    int r = 0;
    for (int m = 0; m < tid; m++) r += (sel_s[m] == e) ? 1 : 0;
    selrk[blockIdx.x * 32 + tid] = (r << 3) | e;
  }
  if (tid < NEXP){
    int hcount = 0;
#pragma unroll
    for (int m = 0; m < 32; m++) hcount += (sel_s[m] == tid) ? 1 : 0;
    blockhist[blockIdx.x * NEXP + tid] = hcount;
    float s = 0.f;
#pragma unroll
    for (int w = 0; w < 16; w++) s += p_s[w][tid];
    impPart[blockIdx.x * NEXP + tid] = s;
  }
}

// ---------------- routing phase 2: exclusive scan of block histograms ----------------
__global__ __launch_bounds__(512) void scan_kernel(int* __restrict__ blockhist,
                                                   const float* __restrict__ impPart,
                                                   int* __restrict__ cnt,
                                                   int* __restrict__ offs,
                                                   float* __restrict__ imp){
  const int e = threadIdx.x >> 6;     // expert 0..7
  const int lane = threadIdx.x & 63;
  const int base = lane * 8;          // 8 blocks per lane, 512 total
  int v[8]; int s = 0;
#pragma unroll
  for (int i = 0; i < 8; i++){
    int tmp = blockhist[(base + i) * NEXP + e];
    v[i] = s; s += tmp;
  }
  int inc = s;
#pragma unroll
  for (int off = 1; off < 64; off <<= 1){
    int o = __shfl_up(inc, off, 64);
    if (lane >= off) inc += o;
  }
  int excl = inc - s;
#pragma unroll
  for (int i = 0; i < 8; i++) blockhist[(base + i) * NEXP + e] = v[i] + excl;
  int tot = __shfl(inc, 63, 64);
  float fs = 0.f;
#pragma unroll
  for (int i = 0; i < 8; i++) fs += impPart[(base + i) * NEXP + e];
#pragma unroll
  for (int off = 32; off; off >>= 1) fs += __shfl_xor(fs, off, 64);
  __shared__ int cnt_s[NEXP];
  if (lane == 0){ cnt_s[e] = tot; cnt[e] = tot; imp[e] = fs; }
  __syncthreads();
  if (threadIdx.x == 0){
    int o = 0;
    for (int q = 0; q < NEXP; q++){ offs[q] = o; o += cnt_s[q]; }
  }
}

// ---------------- routing phase 3: write compact expert lists + slots ----------------
__global__ __launch_bounds__(256) void fill_kernel(const int* __restrict__ selrk,
                                                   const int* __restrict__ blockhist,
                                                   int* __restrict__ elist,
                                                   int4* __restrict__ meta){
  int m = blockIdx.x * 256 + threadIdx.x;   // assignment index, 0..2*NTOK-1
  int t = m >> 1, c = m & 1, b = m >> 5;
  int pk = selrk[m];
  int e = pk & 7, r = pk >> 3;
  int gslot = blockhist[b * NEXP + e] + r;
  elist[e * NTOK + gslot] = t;
  ((int*)meta)[t * 4 + 2 + c] = gslot;
}

// ---------------- 8-phase 256x256 GEMM (BK=64, 8 waves, counted vmcnt, asm ds_read) ----------------
template<int KD, int ND, bool GATHER, bool GELU>
__global__ __launch_bounds__(512) void gemm8p_kernel(const u16* __restrict__ Ag,
                                                     const u16* __restrict__ Bg,
                                                     u16* __restrict__ Cg,
                                                     const int* __restrict__ elist,
                                                     const int* __restrict__ cnt,
                                                     const int* __restrict__ offs){
  const int NBT = ND / 256;
  const int nloc = 32 * NBT;
  const int e  = blockIdx.x / nloc;
  const int rr = blockIdx.x % nloc;
  const int nb = rr / 32;        // consecutive blocks share the B panel (tt inner)
  const int tt = rr % 32;
  const int n_e = cnt[e];
  if (tt * 256 >= n_e) return;

  __shared__ __align__(16) u16 As[2][256 * 64];
  __shared__ __align__(16) u16 Bs[2][256 * 64];

  const int tid = threadIdx.x;
  const int w = tid >> 6, l = tid & 63;
  const int wm = w >> 2, wn = w & 3;           // 2 x 4 wave grid
  const int wrow = wm * 128, wcol = wn * 64;
  const int fr = l & 15, fq = l >> 4;
  const int chunk = (l & 7) ^ ((l >> 3) & 7);  // pre-swizzled global source chunk
  const int row0 = offs[e] + tt * 256;

  // staging addresses: call i covers rows i*64 + w*8 + (l>>3); LDS dest lane-linear
  int srcA[4], srcB[4], ldsO[4];
#pragma unroll
  for (int i = 0; i < 4; i++){
    int rowg = i * 64 + w * 8 + (l >> 3);
    int arow;
    if (GATHER){
      int slot = tt * 256 + rowg;
      if (slot >= n_e) slot = n_e - 1;
      arow = elist[e * NTOK + slot];
    } else {
      arow = row0 + rowg;
    }
    srcA[i] = arow * KD + chunk * 8;
    srcB[i] = (e * ND + nb * 256 + rowg) * KD + chunk * 8;
    ldsO[i] = rowg * 64 + (l & 7) * 8;
  }

  // 32-bit LDS byte addresses for asm ds_read
  const u32 aB = (u32)(uintptr_t)&As[0][0] + (u32)(wrow + fr) * 128u;
  const u32 bB = (u32)(uintptr_t)&Bs[0][0] + (u32)(wcol + fr) * 128u;
  const u32 ck0 = (u32)((fq ^ (fr & 7)) * 16);
  const u32 ck1 = (u32)(((4 + fq) ^ (fr & 7)) * 16);

  const int NKT = KD / 64;
  f32x4 acc[8][4] = {};

  // prologue: stage tiles 0 and 1
#pragma unroll
  for (int i = 0; i < 4; i++){
    gl_lds16(Ag + srcA[i], &As[0][ldsO[i]]);
    gl_lds16(Bg + srcB[i], &Bs[0][ldsO[i]]);
  }
#pragma unroll
  for (int i = 0; i < 4; i++){
    gl_lds16(Ag + srcA[i] + 64, &As[1][ldsO[i]]);
    gl_lds16(Bg + srcB[i] + 64, &Bs[1][ldsO[i]]);
  }
  SCHEDB; VMC8; SCHEDB; BARR; SCHEDB;   // tile 0 ready everywhere

  for (int t = 0; t < NKT; ++t){
    const int p = t & 1;
    const u32 ap = aB + (u32)(p * 32768);
    const u32 bp = bB + (u32)(p * 32768);
    bf16x8 a0[4][2], a1[4][2], b0[2][2], b1[2][2];
    // ---- P0: A-low + B-low reads, MFMA quadrant (m 0..3, n 0..1)
#pragma unroll
    for (int m = 0; m < 4; m++){
      a0[m][0] = ldsr(ap + m * 2048 + ck0);
      a0[m][1] = ldsr(ap + m * 2048 + ck1);
    }
#pragma unroll
    for (int n = 0; n < 2; n++){
      b0[n][0] = ldsr(bp + n * 2048 + ck0);
      b0[n][1] = ldsr(bp + n * 2048 + ck1);
    }
    LGKM0; SCHEDB;
    __builtin_amdgcn_s_setprio(1);
#pragma unroll
    for (int kk = 0; kk < 2; kk++)
#pragma unroll
      for (int m = 0; m < 4; m++)
#pragma unroll
        for (int n = 0; n < 2; n++)
          acc[m][n] = __builtin_amdgcn_mfma_f32_16x16x32_bf16(a0[m][kk], b0[n][kk], acc[m][n], 0, 0, 0);
    __builtin_amdgcn_s_setprio(0);
    // ---- P1: B-high reads, quadrant (m 0..3, n 2..3)
#pragma unroll
    for (int n = 0; n < 2; n++){
      b1[n][0] = ldsr(bp + 4096 + n * 2048 + ck0);
      b1[n][1] = ldsr(bp + 4096 + n * 2048 + ck1);
    }
    LGKM0; SCHEDB;
    __builtin_amdgcn_s_setprio(1);
#pragma unroll
    for (int kk = 0; kk < 2; kk++)
#pragma unroll
      for (int m = 0; m < 4; m++)
#pragma unroll
        for (int n = 0; n < 2; n++)
          acc[m][2 + n] = __builtin_amdgcn_mfma_f32_16x16x32_bf16(a0[m][kk], b1[n][kk], acc[m][2 + n], 0, 0, 0);
    __builtin_amdgcn_s_setprio(0);
    // ---- P2: A-high reads, quadrant (m 4..7, n 0..1)
#pragma unroll
    for (int m = 0; m < 4; m++){
      a1[m][0] = ldsr(ap + 8192 + m * 2048 + ck0);
      a1[m][1] = ldsr(ap + 8192 + m * 2048 + ck1);
    }
    LGKM0; SCHEDB;
    __builtin_amdgcn_s_setprio(1);
#pragma unroll
    for (int kk = 0; kk < 2; kk++)
#pragma unroll
      for (int m = 0; m < 4; m++)
#pragma unroll
        for (int n = 0; n < 2; n++)
          acc[4 + m][n] = __builtin_amdgcn_mfma_f32_16x16x32_bf16(a1[m][kk], b0[n][kk], acc[4 + m][n], 0, 0, 0);
    __builtin_amdgcn_s_setprio(0);
    // ---- P3: buf[p] fully read by all waves -> barrier -> restage buf[p] with tile t+2
    SCHEDB; BARR; SCHEDB;
    if (t + 2 < NKT){
      const int kb = (t + 2) * 64;
#pragma unroll
      for (int i = 0; i < 4; i++){
        gl_lds16(Ag + srcA[i] + kb, &As[p][ldsO[i]]);
        gl_lds16(Bg + srcB[i] + kb, &Bs[p][ldsO[i]]);
      }
    }
    SCHEDB;
    __builtin_amdgcn_s_setprio(1);
#pragma unroll
    for (int kk = 0; kk < 2; kk++)
#pragma unroll
      for (int m = 0; m < 4; m++)
#pragma unroll
        for (int n = 0; n < 2; n++)
          acc[4 + m][2 + n] = __builtin_amdgcn_mfma_f32_16x16x32_bf16(a1[m][kk], b1[n][kk], acc[4 + m][2 + n], 0, 0, 0);
    __builtin_amdgcn_s_setprio(0);
    if (t + 1 < NKT){
      SCHEDB;
      if (t + 2 < NKT) { VMC8; } else { VMC0; }   // tile t+1 ready; never drain live prefetch
      SCHEDB; BARR; SCHEDB;
    }
  }

  // epilogue
  const int c0 = nb * 256 + wcol;
#pragma unroll
  for (int m = 0; m < 8; m++){
#pragma unroll
    for (int j = 0; j < 4; j++){
      int slot = tt * 256 + wrow + m * 16 + fq * 4 + j;
      if (slot >= n_e) continue;
      long base = (long)(offs[e] + slot) * ND + c0;
#pragma unroll
      for (int n = 0; n < 4; n++){
        float v = acc[m][n][j];
        if (GELU) v = 0.5f * v * (1.0f + erff(v * 0.70710678118f));
        Cg[base + n * 16 + fr] = f2bf(v);
      }
    }
  }
}

// ---------------- combine: out[t] = g0*y0 + g1*y1 ----------------
__global__ __launch_bounds__(256) void combine_kernel(const u16* __restrict__ ypair,
                                                      const int4* __restrict__ meta,
                                                      const float2* __restrict__ gates,
                                                      const int* __restrict__ offs,
                                                      float* __restrict__ out){
  int t = blockIdx.x;
  int c = threadIdx.x;
  int4 m = meta[t];
  float2 g = gates[t];
  long p0 = (long)(offs[m.x] + m.z) * DDIM + c * 4;
  long p1 = (long)(offs[m.y] + m.w) * DDIM + c * 4;
  u16x4 y0 = *(const u16x4*)&ypair[p0];
  u16x4 y1 = *(const u16x4*)&ypair[p1];
  float4 o;
  o.x = g.x * bf2f(y0[0]) + g.y * bf2f(y1[0]);
  o.y = g.x * bf2f(y0[1]) + g.y * bf2f(y1[1]);
  o.z = g.x * bf2f(y0[2]) + g.y * bf2f(y1[2]);
  o.w = g.x * bf2f(y0[3]) + g.y * bf2f(y1[3]);
  *(float4*)&out[(long)t * DDIM + c * 4] = o;
}

// ---------------- load-balance loss ----------------
__global__ void lb_kernel(const float* __restrict__ imp, const int* __restrict__ cnt,
                          float* __restrict__ outp){
  if (threadIdx.x == 0 && blockIdx.x == 0){
    float si = 0.f, sl = 0.f;
    for (int e = 0; e < NEXP; e++){ si += imp[e]; sl += (float)cnt[e]; }
    float lb = 0.f;
    for (int e = 0; e < NEXP; e++)
      lb += (imp[e] / (si + 1e-9f)) * ((float)cnt[e] / (sl + 1e-9f));
    outp[0] = lb * (float)NEXP;
  }
}

extern "C" void kernel_launch(void* const* d_in, const int* in_sizes, int n_in,
                              void* d_out, int out_size, void* d_ws, size_t ws_size,
                              hipStream_t stream){
  const float* x  = (const float*)d_in[0];
  const float* Wr = (const float*)d_in[1];
  const float* W1 = (const float*)d_in[2];
  const float* W2 = (const float*)d_in[3];
  float* out = (float*)d_out;
  char* ws = (char*)d_ws;
  size_t off = 0;
  u16* xb = (u16*)(ws + off);   off += (size_t)NTOK * DDIM * 2;
  u16* wt = (u16*)(ws + off);   off += (size_t)NEXP * DDIM * HDIM * 2;   // reused: W1^T then W2^T
  u16* h  = (u16*)(ws + off);   off += (size_t)HROWS * HDIM * 2;
  u16* yp = (u16*)(ws + off);   off += (size_t)NTOK * 2 * DDIM * 2;
  int* elist    = (int*)(ws + off);    off += (size_t)NEXP * NTOK * 4;
  int4* meta    = (int4*)(ws + off);   off += (size_t)NTOK * 16;
  float2* gts   = (float2*)(ws + off); off += (size_t)NTOK * 8;
  int* selrk    = (int*)(ws + off);    off += (size_t)NTOK * 2 * 4;
  int* bhist    = (int*)(ws + off);    off += (size_t)RBLK * NEXP * 4;
  float* impP   = (float*)(ws + off);  off += (size_t)RBLK * NEXP * 4;
  int* cnt      = (int*)(ws + off);    off += 32;
  float* imp    = (float*)(ws + off);  off += 32;
  int* offs     = (int*)(ws + off);    off += 32;
  if (ws_size < off) return;  // insufficient workspace: fail visibly

  cvtx_kernel<<<4096, 256, 0, stream>>>(x, xb);
  route_kernel<<<RBLK, 1024, 0, stream>>>(x, Wr, meta, gts, selrk, bhist, impP);
  scan_kernel<<<1, 512, 0, stream>>>(bhist, impP, cnt, offs, imp);
  fill_kernel<<<NTOK * 2 / 256, 256, 0, stream>>>(selrk, bhist, elist, meta);
  transpose_cvt<<<dim3(HDIM / 64, DDIM / 64, NEXP), 256, 0, stream>>>(W1, wt, DDIM, HDIM);
  gemm8p_kernel<DDIM, HDIM, true, true><<<NEXP * 32 * (HDIM / 256), 512, 0, stream>>>(
      xb, wt, h, elist, cnt, offs);
  transpose_cvt<<<dim3(DDIM / 64, HDIM / 64, NEXP), 256, 0, stream>>>(W2, wt, HDIM, DDIM);
  gemm8p_kernel<HDIM, DDIM, false, false><<<NEXP * 32 * (DDIM / 256), 512, 0, stream>>>(
      h, wt, yp, elist, cnt, offs);
  combine_kernel<<<NTOK, 256, 0, stream>>>(yp, meta, gts, offs, out);
  lb_kernel<<<1, 64, 0, stream>>>(imp, cnt, out + (size_t)NTOK * DDIM);
}

// Round 6
// 566.476 us; speedup vs baseline: 2.4483x; 2.4023x over previous
//
#include <hip/hip_runtime.h>
#include <hip/hip_bf16.h>
#include <math.h>

#define NTOK 8192      // B*T = 4*2048
#define DDIM 1024
#define HDIM 4096
#define NEXP 8
#define HROWS (NTOK*2 + 256)   // compact pair rows + pad for ragged tile overread
#define RBLK 512               // route blocks (16 tokens each)

typedef unsigned int u32;
typedef unsigned short u16;
typedef __bf16 bf16x8 __attribute__((ext_vector_type(8)));
typedef float f32x4 __attribute__((ext_vector_type(4)));
typedef u16 u16x8 __attribute__((ext_vector_type(8)));
typedef u16 u16x4 __attribute__((ext_vector_type(4)));

__device__ __forceinline__ u16 f2bf(float f){
  u32 u = __builtin_bit_cast(u32, f);
  u32 r = (u + 0x7FFFu + ((u >> 16) & 1u)) >> 16;   // RNE
  return (u16)r;
}
__device__ __forceinline__ float bf2f(u16 b){
  u32 u = ((u32)b) << 16;
  return __builtin_bit_cast(float, u);
}
__device__ __forceinline__ void gl_lds16(const void* g, void* l){
  __builtin_amdgcn_global_load_lds(
      (const __attribute__((address_space(1))) u32*)g,
      (__attribute__((address_space(3))) u32*)l, 16, 0, 0);
}

// ---------------- convert x fp32 -> bf16 ----------------
__global__ __launch_bounds__(256) void cvtx_kernel(const float* __restrict__ x,
                                                   u16* __restrict__ xb){
  long i = (long)(blockIdx.x * 256 + threadIdx.x) * 8;
  float4 a = *(const float4*)(x + i);
  float4 b = *(const float4*)(x + i + 4);
  u16x8 o;
  o[0]=f2bf(a.x); o[1]=f2bf(a.y); o[2]=f2bf(a.z); o[3]=f2bf(a.w);
  o[4]=f2bf(b.x); o[5]=f2bf(b.y); o[6]=f2bf(b.z); o[7]=f2bf(b.w);
  *(u16x8*)(xb + i) = o;
}

// ------------- transpose+convert: in [R][C] fp32 -> out [C][R] bf16, per expert -------------
__global__ __launch_bounds__(256) void transpose_cvt(const float* __restrict__ in,
                                                     u16* __restrict__ out,
                                                     int R, int C){
  int e = blockIdx.z;
  const float* pin = in + (long)e * R * C;
  u16* pout = out + (long)e * R * C;
  __shared__ u16 tile[64][65];
  int c0 = blockIdx.x * 64, r0 = blockIdx.y * 64;
  int tid = threadIdx.x;
#pragma unroll
  for (int j = 0; j < 16; j++){
    int idx = tid + 256 * j;
    int r = idx >> 6, c = idx & 63;
    tile[r][c] = f2bf(pin[(long)(r0 + r) * C + c0 + c]);
  }
  __syncthreads();
#pragma unroll
  for (int j = 0; j < 16; j++){
    int idx = tid + 256 * j;
    int r = idx >> 6, c = idx & 63;
    pout[(long)(c0 + r) * R + r0 + c] = tile[c][r];
  }
}

// ---------------- routing phase 1: 1 wave per token, no global atomics ----------------
__global__ __launch_bounds__(1024) void route_kernel(const float* __restrict__ x,
                                                     const float* __restrict__ Wr,
                                                     int4* __restrict__ meta,
                                                     float2* __restrict__ gates,
                                                     int* __restrict__ selrk,
                                                     int* __restrict__ blockhist,
                                                     float* __restrict__ impPart){
  const int wid = threadIdx.x >> 6;       // 0..15 (token within block)
  const int lane = threadIdx.x & 63;
  const int t = blockIdx.x * 16 + wid;
  const float* xr = x + (long)t * DDIM;
  float acc[NEXP] = {};
  for (int d0 = lane * 4; d0 < DDIM; d0 += 256){
    float4 xv = *(const float4*)(xr + d0);
    const float* w = Wr + d0 * NEXP;
#pragma unroll
    for (int q = 0; q < 4; q++){
      float xq = ((const float*)&xv)[q];
      float4 w0 = *(const float4*)(w + q * NEXP);
      float4 w1 = *(const float4*)(w + q * NEXP + 4);
      acc[0] += xq * w0.x; acc[1] += xq * w0.y; acc[2] += xq * w0.z; acc[3] += xq * w0.w;
      acc[4] += xq * w1.x; acc[5] += xq * w1.y; acc[6] += xq * w1.z; acc[7] += xq * w1.w;
    }
  }
#pragma unroll
  for (int e = 0; e < NEXP; e++){
#pragma unroll
    for (int off = 32; off; off >>= 1) acc[e] += __shfl_xor(acc[e], off, 64);
  }
  __shared__ int sel_s[32];
  __shared__ float p_s[16][NEXP];
  if (lane == 0){
    float mx = acc[0];
#pragma unroll
    for (int e = 1; e < NEXP; e++) mx = fmaxf(mx, acc[e]);
    float p[NEXP]; float s = 0.f;
#pragma unroll
    for (int e = 0; e < NEXP; e++){ p[e] = expf(acc[e] - mx); s += p[e]; }
    float inv = 1.f / s;
#pragma unroll
    for (int e = 0; e < NEXP; e++){ p[e] *= inv; p_s[wid][e] = p[e]; }
    int i0 = 0; float v0 = p[0];
#pragma unroll
    for (int e = 1; e < NEXP; e++) if (p[e] > v0){ v0 = p[e]; i0 = e; }
    int i1 = -1; float v1 = -1.f;
#pragma unroll
    for (int e = 0; e < NEXP; e++) if (e != i0 && p[e] > v1){ v1 = p[e]; i1 = e; }
    float gs = v0 + v1 + 1e-9f;
    meta[t] = make_int4(i0, i1, 0, 0);
    gates[t] = make_float2(v0 / gs, v1 / gs);
    sel_s[wid * 2] = i0;
    sel_s[wid * 2 + 1] = i1;
  }
  __syncthreads();
  const int tid = threadIdx.x;
  if (tid < 32){
    int e = sel_s[tid];
    int r = 0;
    for (int m = 0; m < tid; m++) r += (sel_s[m] == e) ? 1 : 0;
    selrk[blockIdx.x * 32 + tid] = (r << 3) | e;
  }
  if (tid < NEXP){
    int hcount = 0;
#pragma unroll
    for (int m = 0; m < 32; m++) hcount += (sel_s[m] == tid) ? 1 : 0;
    blockhist[blockIdx.x * NEXP + tid] = hcount;
    float s = 0.f;
#pragma unroll
    for (int w = 0; w < 16; w++) s += p_s[w][tid];
    impPart[blockIdx.x * NEXP + tid] = s;
  }
}

// ---------------- routing phase 2: exclusive scan of block histograms ----------------
__global__ __launch_bounds__(512) void scan_kernel(int* __restrict__ blockhist,
                                                   const float* __restrict__ impPart,
                                                   int* __restrict__ cnt,
                                                   int* __restrict__ offs,
                                                   float* __restrict__ imp){
  const int e = threadIdx.x >> 6;     // expert 0..7
  const int lane = threadIdx.x & 63;
  const int base = lane * 8;          // 8 blocks per lane, 512 total
  int v[8]; int s = 0;
#pragma unroll
  for (int i = 0; i < 8; i++){
    int tmp = blockhist[(base + i) * NEXP + e];
    v[i] = s; s += tmp;
  }
  int inc = s;
#pragma unroll
  for (int off = 1; off < 64; off <<= 1){
    int o = __shfl_up(inc, off, 64);
    if (lane >= off) inc += o;
  }
  int excl = inc - s;
#pragma unroll
  for (int i = 0; i < 8; i++) blockhist[(base + i) * NEXP + e] = v[i] + excl;
  int tot = __shfl(inc, 63, 64);
  float fs = 0.f;
#pragma unroll
  for (int i = 0; i < 8; i++) fs += impPart[(base + i) * NEXP + e];
#pragma unroll
  for (int off = 32; off; off >>= 1) fs += __shfl_xor(fs, off, 64);
  __shared__ int cnt_s[NEXP];
  if (lane == 0){ cnt_s[e] = tot; cnt[e] = tot; imp[e] = fs; }
  __syncthreads();
  if (threadIdx.x == 0){
    int o = 0;
    for (int q = 0; q < NEXP; q++){ offs[q] = o; o += cnt_s[q]; }
  }
}

// ---------------- routing phase 3: write compact expert lists + slots ----------------
__global__ __launch_bounds__(256) void fill_kernel(const int* __restrict__ selrk,
                                                   const int* __restrict__ blockhist,
                                                   int* __restrict__ elist,
                                                   int4* __restrict__ meta){
  int m = blockIdx.x * 256 + threadIdx.x;   // assignment index, 0..2*NTOK-1
  int t = m >> 1, c = m & 1, b = m >> 5;
  int pk = selrk[m];
  int e = pk & 7, r = pk >> 3;
  int gslot = blockhist[b * NEXP + e] + r;
  elist[e * NTOK + gslot] = t;
  ((int*)meta)[t * 4 + 2 + c] = gslot;
}

// ---- 128x128 GEMM, BK=64, single-buffer LDS, R2 structure + validated T2 swizzle ----
// grid: (x = ND/128 output-col tiles, y = row tiles, z = expert)
template<int KD, int ND, bool GATHER, bool GELU>
__global__ __launch_bounds__(256) void gemm128_kernel(const u16* __restrict__ Ag,
                                                      const u16* __restrict__ Bg,
                                                      u16* __restrict__ Cg,
                                                      const int* __restrict__ elist,
                                                      const int* __restrict__ cnt,
                                                      const int* __restrict__ offs){
  const int e = blockIdx.z;
  const int n_e = cnt[e];
  const int tt = blockIdx.y;
  if (tt * 128 >= n_e) return;
  const int cb = blockIdx.x * 128;
  __shared__ __align__(16) u16 As[128 * 64];
  __shared__ __align__(16) u16 Bs[128 * 64];
  const int tid = threadIdx.x;
  const int csrc = (((tid & 7) ^ ((tid >> 3) & 7)) << 3);   // swizzled global source chunk
  const int clin = (tid & 7) << 3;                          // linear LDS dest chunk
  const int row0 = offs[e] + tt * 128;
  const long bbase = ((long)e * ND + cb) * KD;
  long agb[4], bgb[4]; int lrow[4];
#pragma unroll
  for (int q = 0; q < 4; q++){
    int row = q * 32 + (tid >> 3);
    int arow;
    if (GATHER){
      int slot = tt * 128 + row;
      if (slot >= n_e) slot = n_e - 1;
      arow = elist[e * NTOK + slot];
    } else {
      arow = row0 + row;
    }
    lrow[q] = row;
    agb[q] = (long)arow * KD + csrc;
    bgb[q] = bbase + (long)row * KD + csrc;
  }
  const int wid = tid >> 6, lane = tid & 63;
  const int wr = (wid >> 1) * 64, wc = (wid & 1) * 64;
  const int fr = lane & 15, fq = lane >> 4;
  f32x4 acc[4][4] = {};
  for (int kb = 0; kb < KD; kb += 64){
    __syncthreads();
#pragma unroll
    for (int q = 0; q < 4; q++){
      gl_lds16(Ag + agb[q] + kb, &As[lrow[q] * 64 + clin]);
      gl_lds16(Bg + bgb[q] + kb, &Bs[lrow[q] * 64 + clin]);
    }
    __syncthreads();
#pragma unroll
    for (int kk = 0; kk < 2; kk++){
      bf16x8 af[4], bfr[4];
#pragma unroll
      for (int m = 0; m < 4; m++){
        int r = wr + m * 16 + fr;
        int coff = (((kk * 4 + fq) ^ (r & 7)) << 3);
        af[m] = *(const bf16x8*)&As[r * 64 + coff];
      }
#pragma unroll
      for (int n = 0; n < 4; n++){
        int r = wc + n * 16 + fr;
        int coff = (((kk * 4 + fq) ^ (r & 7)) << 3);
        bfr[n] = *(const bf16x8*)&Bs[r * 64 + coff];
      }
#pragma unroll
      for (int m = 0; m < 4; m++)
#pragma unroll
        for (int n = 0; n < 4; n++)
          acc[m][n] = __builtin_amdgcn_mfma_f32_16x16x32_bf16(af[m], bfr[n], acc[m][n], 0, 0, 0);
    }
  }
#pragma unroll
  for (int m = 0; m < 4; m++){
#pragma unroll
    for (int j = 0; j < 4; j++){
      int row = wr + m * 16 + fq * 4 + j;
      int slot = tt * 128 + row;
      if (slot >= n_e) continue;
      long base = (long)(row0 + row) * ND + cb + wc;
#pragma unroll
      for (int n = 0; n < 4; n++){
        float v = acc[m][n][j];
        if (GELU) v = 0.5f * v * (1.0f + erff(v * 0.70710678118f));   // exact gelu
        Cg[base + n * 16 + fr] = f2bf(v);
      }
    }
  }
}

// ---------------- combine: out[t] = g0*y0 + g1*y1 ----------------
__global__ __launch_bounds__(256) void combine_kernel(const u16* __restrict__ ypair,
                                                      const int4* __restrict__ meta,
                                                      const float2* __restrict__ gates,
                                                      const int* __restrict__ offs,
                                                      float* __restrict__ out){
  int t = blockIdx.x;
  int c = threadIdx.x;
  int4 m = meta[t];
  float2 g = gates[t];
  long p0 = (long)(offs[m.x] + m.z) * DDIM + c * 4;
  long p1 = (long)(offs[m.y] + m.w) * DDIM + c * 4;
  u16x4 y0 = *(const u16x4*)&ypair[p0];
  u16x4 y1 = *(const u16x4*)&ypair[p1];
  float4 o;
  o.x = g.x * bf2f(y0[0]) + g.y * bf2f(y1[0]);
  o.y = g.x * bf2f(y0[1]) + g.y * bf2f(y1[1]);
  o.z = g.x * bf2f(y0[2]) + g.y * bf2f(y1[2]);
  o.w = g.x * bf2f(y0[3]) + g.y * bf2f(y1[3]);
  *(float4*)&out[(long)t * DDIM + c * 4] = o;
}

// ---------------- load-balance loss ----------------
__global__ void lb_kernel(const float* __restrict__ imp, const int* __restrict__ cnt,
                          float* __restrict__ outp){
  if (threadIdx.x == 0 && blockIdx.x == 0){
    float si = 0.f, sl = 0.f;
    for (int e = 0; e < NEXP; e++){ si += imp[e]; sl += (float)cnt[e]; }
    float lb = 0.f;
    for (int e = 0; e < NEXP; e++)
      lb += (imp[e] / (si + 1e-9f)) * ((float)cnt[e] / (sl + 1e-9f));
    outp[0] = lb * (float)NEXP;
  }
}

extern "C" void kernel_launch(void* const* d_in, const int* in_sizes, int n_in,
                              void* d_out, int out_size, void* d_ws, size_t ws_size,
                              hipStream_t stream){
  const float* x  = (const float*)d_in[0];
  const float* Wr = (const float*)d_in[1];
  const float* W1 = (const float*)d_in[2];
  const float* W2 = (const float*)d_in[3];
  float* out = (float*)d_out;
  char* ws = (char*)d_ws;
  size_t off = 0;
  u16* xb = (u16*)(ws + off);   off += (size_t)NTOK * DDIM * 2;
  u16* wt = (u16*)(ws + off);   off += (size_t)NEXP * DDIM * HDIM * 2;   // reused: W1^T then W2^T
  u16* h  = (u16*)(ws + off);   off += (size_t)HROWS * HDIM * 2;
  u16* yp = (u16*)(ws + off);   off += (size_t)NTOK * 2 * DDIM * 2;
  int* elist    = (int*)(ws + off);    off += (size_t)NEXP * NTOK * 4;
  int4* meta    = (int4*)(ws + off);   off += (size_t)NTOK * 16;
  float2* gts   = (float2*)(ws + off); off += (size_t)NTOK * 8;
  int* selrk    = (int*)(ws + off);    off += (size_t)NTOK * 2 * 4;
  int* bhist    = (int*)(ws + off);    off += (size_t)RBLK * NEXP * 4;
  float* impP   = (float*)(ws + off);  off += (size_t)RBLK * NEXP * 4;
  int* cnt      = (int*)(ws + off);    off += 32;
  float* imp    = (float*)(ws + off);  off += 32;
  int* offs     = (int*)(ws + off);    off += 32;
  if (ws_size < off) return;  // insufficient workspace: fail visibly

  cvtx_kernel<<<4096, 256, 0, stream>>>(x, xb);
  route_kernel<<<RBLK, 1024, 0, stream>>>(x, Wr, meta, gts, selrk, bhist, impP);
  scan_kernel<<<1, 512, 0, stream>>>(bhist, impP, cnt, offs, imp);
  fill_kernel<<<NTOK * 2 / 256, 256, 0, stream>>>(selrk, bhist, elist, meta);
  transpose_cvt<<<dim3(HDIM / 64, DDIM / 64, NEXP), 256, 0, stream>>>(W1, wt, DDIM, HDIM);
  gemm128_kernel<DDIM, HDIM, true, true><<<dim3(HDIM / 128, NTOK / 128, NEXP), 256, 0, stream>>>(
      xb, wt, h, elist, cnt, offs);
  transpose_cvt<<<dim3(DDIM / 64, HDIM / 64, NEXP), 256, 0, stream>>>(W2, wt, HDIM, DDIM);
  gemm128_kernel<HDIM, DDIM, false, false><<<dim3(DDIM / 128, NTOK / 128, NEXP), 256, 0, stream>>>(
      h, wt, yp, elist, cnt, offs);
  combine_kernel<<<NTOK, 256, 0, stream>>>(yp, meta, gts, offs, out);
  lb_kernel<<<1, 64, 0, stream>>>(imp, cnt, out + (size_t)NTOK * DDIM);
}

// Round 7
// 542.232 us; speedup vs baseline: 2.5578x; 1.0447x over previous
//
#include <hip/hip_runtime.h>
#include <hip/hip_bf16.h>
#include <math.h>

#define NTOK 8192      // B*T = 4*2048
#define DDIM 1024
#define HDIM 4096
#define NEXP 8
#define HROWS (NTOK*2 + 256)   // compact pair rows + pad for ragged tile overread
#define RBLK 512               // route blocks (16 tokens each)

typedef unsigned int u32;
typedef unsigned short u16;
typedef __bf16 bf16x8 __attribute__((ext_vector_type(8)));
typedef float f32x4 __attribute__((ext_vector_type(4)));
typedef u16 u16x8 __attribute__((ext_vector_type(8)));
typedef u16 u16x4 __attribute__((ext_vector_type(4)));

__device__ __forceinline__ u16 f2bf(float f){
  u32 u = __builtin_bit_cast(u32, f);
  u32 r = (u + 0x7FFFu + ((u >> 16) & 1u)) >> 16;   // RNE
  return (u16)r;
}
__device__ __forceinline__ float bf2f(u16 b){
  u32 u = ((u32)b) << 16;
  return __builtin_bit_cast(float, u);
}
__device__ __forceinline__ void gl_lds16(const void* g, void* l){
  __builtin_amdgcn_global_load_lds(
      (const __attribute__((address_space(1))) u32*)g,
      (__attribute__((address_space(3))) u32*)l, 16, 0, 0);
}
// tanh-form gelu (max |err| vs exact erf-gelu ~1e-3, far inside tolerance)
__device__ __forceinline__ float gelu_t(float v){
  float u = v * (0.7978845608f + 0.0356774081f * v * v);
  float e = __expf(2.0f * u);
  float t = 1.0f - 2.0f / (e + 1.0f);    // tanh(u)
  return 0.5f * v * (1.0f + t);
}

// ---------------- convert x fp32 -> bf16 ----------------
__global__ __launch_bounds__(256) void cvtx_kernel(const float* __restrict__ x,
                                                   u16* __restrict__ xb){
  long i = (long)(blockIdx.x * 256 + threadIdx.x) * 8;
  float4 a = *(const float4*)(x + i);
  float4 b = *(const float4*)(x + i + 4);
  u16x8 o;
  o[0]=f2bf(a.x); o[1]=f2bf(a.y); o[2]=f2bf(a.z); o[3]=f2bf(a.w);
  o[4]=f2bf(b.x); o[5]=f2bf(b.y); o[6]=f2bf(b.z); o[7]=f2bf(b.w);
  *(u16x8*)(xb + i) = o;
}

// ------------- transpose+convert: in [R][C] fp32 -> out [C][R] bf16, per expert -------------
__global__ __launch_bounds__(256) void transpose_cvt(const float* __restrict__ in,
                                                     u16* __restrict__ out,
                                                     int R, int C){
  int e = blockIdx.z;
  const float* pin = in + (long)e * R * C;
  u16* pout = out + (long)e * R * C;
  __shared__ u16 tile[64][65];
  int c0 = blockIdx.x * 64, r0 = blockIdx.y * 64;
  int tid = threadIdx.x;
#pragma unroll
  for (int j = 0; j < 16; j++){
    int idx = tid + 256 * j;
    int r = idx >> 6, c = idx & 63;
    tile[r][c] = f2bf(pin[(long)(r0 + r) * C + c0 + c]);
  }
  __syncthreads();
#pragma unroll
  for (int j = 0; j < 16; j++){
    int idx = tid + 256 * j;
    int r = idx >> 6, c = idx & 63;
    pout[(long)(c0 + r) * R + r0 + c] = tile[c][r];
  }
}

// ---------------- routing phase 1: 1 wave per token, no global atomics ----------------
__global__ __launch_bounds__(1024) void route_kernel(const float* __restrict__ x,
                                                     const float* __restrict__ Wr,
                                                     int4* __restrict__ meta,
                                                     float2* __restrict__ gates,
                                                     int* __restrict__ selrk,
                                                     int* __restrict__ blockhist,
                                                     float* __restrict__ impPart){
  const int wid = threadIdx.x >> 6;       // 0..15 (token within block)
  const int lane = threadIdx.x & 63;
  const int t = blockIdx.x * 16 + wid;
  const float* xr = x + (long)t * DDIM;
  float acc[NEXP] = {};
  for (int d0 = lane * 4; d0 < DDIM; d0 += 256){
    float4 xv = *(const float4*)(xr + d0);
    const float* w = Wr + d0 * NEXP;
#pragma unroll
    for (int q = 0; q < 4; q++){
      float xq = ((const float*)&xv)[q];
      float4 w0 = *(const float4*)(w + q * NEXP);
      float4 w1 = *(const float4*)(w + q * NEXP + 4);
      acc[0] += xq * w0.x; acc[1] += xq * w0.y; acc[2] += xq * w0.z; acc[3] += xq * w0.w;
      acc[4] += xq * w1.x; acc[5] += xq * w1.y; acc[6] += xq * w1.z; acc[7] += xq * w1.w;
    }
  }
#pragma unroll
  for (int e = 0; e < NEXP; e++){
#pragma unroll
    for (int off = 32; off; off >>= 1) acc[e] += __shfl_xor(acc[e], off, 64);
  }
  __shared__ int sel_s[32];
  __shared__ float p_s[16][NEXP];
  if (lane == 0){
    float mx = acc[0];
#pragma unroll
    for (int e = 1; e < NEXP; e++) mx = fmaxf(mx, acc[e]);
    float p[NEXP]; float s = 0.f;
#pragma unroll
    for (int e = 0; e < NEXP; e++){ p[e] = expf(acc[e] - mx); s += p[e]; }
    float inv = 1.f / s;
#pragma unroll
    for (int e = 0; e < NEXP; e++){ p[e] *= inv; p_s[wid][e] = p[e]; }
    int i0 = 0; float v0 = p[0];
#pragma unroll
    for (int e = 1; e < NEXP; e++) if (p[e] > v0){ v0 = p[e]; i0 = e; }
    int i1 = -1; float v1 = -1.f;
#pragma unroll
    for (int e = 0; e < NEXP; e++) if (e != i0 && p[e] > v1){ v1 = p[e]; i1 = e; }
    float gs = v0 + v1 + 1e-9f;
    meta[t] = make_int4(i0, i1, 0, 0);
    gates[t] = make_float2(v0 / gs, v1 / gs);
    sel_s[wid * 2] = i0;
    sel_s[wid * 2 + 1] = i1;
  }
  __syncthreads();
  const int tid = threadIdx.x;
  if (tid < 32){
    int e = sel_s[tid];
    int r = 0;
    for (int m = 0; m < tid; m++) r += (sel_s[m] == e) ? 1 : 0;
    selrk[blockIdx.x * 32 + tid] = (r << 3) | e;
  }
  if (tid < NEXP){
    int hcount = 0;
#pragma unroll
    for (int m = 0; m < 32; m++) hcount += (sel_s[m] == tid) ? 1 : 0;
    blockhist[blockIdx.x * NEXP + tid] = hcount;
    float s = 0.f;
#pragma unroll
    for (int w = 0; w < 16; w++) s += p_s[w][tid];
    impPart[blockIdx.x * NEXP + tid] = s;
  }
}

// ---------------- routing phase 2: exclusive scan of block histograms ----------------
__global__ __launch_bounds__(512) void scan_kernel(int* __restrict__ blockhist,
                                                   const float* __restrict__ impPart,
                                                   int* __restrict__ cnt,
                                                   int* __restrict__ offs,
                                                   float* __restrict__ imp){
  const int e = threadIdx.x >> 6;     // expert 0..7
  const int lane = threadIdx.x & 63;
  const int base = lane * 8;          // 8 blocks per lane, 512 total
  int v[8]; int s = 0;
#pragma unroll
  for (int i = 0; i < 8; i++){
    int tmp = blockhist[(base + i) * NEXP + e];
    v[i] = s; s += tmp;
  }
  int inc = s;
#pragma unroll
  for (int off = 1; off < 64; off <<= 1){
    int o = __shfl_up(inc, off, 64);
    if (lane >= off) inc += o;
  }
  int excl = inc - s;
#pragma unroll
  for (int i = 0; i < 8; i++) blockhist[(base + i) * NEXP + e] = v[i] + excl;
  int tot = __shfl(inc, 63, 64);
  float fs = 0.f;
#pragma unroll
  for (int i = 0; i < 8; i++) fs += impPart[(base + i) * NEXP + e];
#pragma unroll
  for (int off = 32; off; off >>= 1) fs += __shfl_xor(fs, off, 64);
  __shared__ int cnt_s[NEXP];
  if (lane == 0){ cnt_s[e] = tot; cnt[e] = tot; imp[e] = fs; }
  __syncthreads();
  if (threadIdx.x == 0){
    int o = 0;
    for (int q = 0; q < NEXP; q++){ offs[q] = o; o += cnt_s[q]; }
  }
}

// ---------------- routing phase 3: write compact expert lists + slots ----------------
__global__ __launch_bounds__(256) void fill_kernel(const int* __restrict__ selrk,
                                                   const int* __restrict__ blockhist,
                                                   int* __restrict__ elist,
                                                   int4* __restrict__ meta){
  int m = blockIdx.x * 256 + threadIdx.x;   // assignment index, 0..2*NTOK-1
  int t = m >> 1, c = m & 1, b = m >> 5;
  int pk = selrk[m];
  int e = pk & 7, r = pk >> 3;
  int gslot = blockhist[b * NEXP + e] + r;
  elist[e * NTOK + gslot] = t;
  ((int*)meta)[t * 4 + 2 + c] = gslot;
}

// ---- 128x128 GEMM, BK=64, single-buffer LDS, T2 swizzle, hoisted LDS addressing ----
// grid: (x = ND/128 output-col tiles, y = row tiles, z = expert)
template<int KD, int ND, bool GATHER, bool GELU>
__global__ __launch_bounds__(256) void gemm128_kernel(const u16* __restrict__ Ag,
                                                      const u16* __restrict__ Bg,
                                                      u16* __restrict__ Cg,
                                                      const int* __restrict__ elist,
                                                      const int* __restrict__ cnt,
                                                      const int* __restrict__ offs){
  const int e = blockIdx.z;
  const int n_e = cnt[e];
  const int tt = blockIdx.y;
  if (tt * 128 >= n_e) return;
  const int cb = blockIdx.x * 128;
  __shared__ __align__(16) u16 As[128 * 64];
  __shared__ __align__(16) u16 Bs[128 * 64];
  const int tid = threadIdx.x;
  const int csrc = (((tid & 7) ^ ((tid >> 3) & 7)) << 3);   // swizzled global source chunk
  const int clin = (tid & 7) << 3;                          // linear LDS dest chunk
  const int row0 = offs[e] + tt * 128;
  const long bbase = ((long)e * ND + cb) * KD;
  long agb[4], bgb[4]; int lrow[4];
#pragma unroll
  for (int q = 0; q < 4; q++){
    int row = q * 32 + (tid >> 3);
    int arow;
    if (GATHER){
      int slot = tt * 128 + row;
      if (slot >= n_e) slot = n_e - 1;
      arow = elist[e * NTOK + slot];
    } else {
      arow = row0 + row;
    }
    lrow[q] = row;
    agb[q] = (long)arow * KD + csrc;
    bgb[q] = bbase + (long)row * KD + csrc;
  }
  const int wid = tid >> 6, lane = tid & 63;
  const int wr = (wid >> 1) * 64, wc = (wid & 1) * 64;
  const int fr = lane & 15, fq = lane >> 4;
  // K-invariant swizzled fragment base pointers (r&7 == fr&7 for all fragment rows)
  const int sw0 = (fq ^ (fr & 7)) << 3;          // kk = 0 chunk byte offset (elems)
  const int sw1 = ((4 + fq) ^ (fr & 7)) << 3;    // kk = 1
  const u16* aP0 = &As[(wr + fr) * 64 + sw0];
  const u16* aP1 = &As[(wr + fr) * 64 + sw1];
  const u16* bP0 = &Bs[(wc + fr) * 64 + sw0];
  const u16* bP1 = &Bs[(wc + fr) * 64 + sw1];
  f32x4 acc[4][4] = {};
  for (int kb = 0; kb < KD; kb += 64){
    __syncthreads();
#pragma unroll
    for (int q = 0; q < 4; q++){
      gl_lds16(Ag + agb[q] + kb, &As[lrow[q] * 64 + clin]);
      gl_lds16(Bg + bgb[q] + kb, &Bs[lrow[q] * 64 + clin]);
    }
    __syncthreads();
    {
      bf16x8 af[4], bfr[4];
#pragma unroll
      for (int m = 0; m < 4; m++) af[m] = *(const bf16x8*)(aP0 + m * 1024);
#pragma unroll
      for (int n = 0; n < 4; n++) bfr[n] = *(const bf16x8*)(bP0 + n * 1024);
#pragma unroll
      for (int m = 0; m < 4; m++)
#pragma unroll
        for (int n = 0; n < 4; n++)
          acc[m][n] = __builtin_amdgcn_mfma_f32_16x16x32_bf16(af[m], bfr[n], acc[m][n], 0, 0, 0);
    }
    {
      bf16x8 af[4], bfr[4];
#pragma unroll
      for (int m = 0; m < 4; m++) af[m] = *(const bf16x8*)(aP1 + m * 1024);
#pragma unroll
      for (int n = 0; n < 4; n++) bfr[n] = *(const bf16x8*)(bP1 + n * 1024);
#pragma unroll
      for (int m = 0; m < 4; m++)
#pragma unroll
        for (int n = 0; n < 4; n++)
          acc[m][n] = __builtin_amdgcn_mfma_f32_16x16x32_bf16(af[m], bfr[n], acc[m][n], 0, 0, 0);
    }
  }
#pragma unroll
  for (int m = 0; m < 4; m++){
#pragma unroll
    for (int j = 0; j < 4; j++){
      int row = wr + m * 16 + fq * 4 + j;
      int slot = tt * 128 + row;
      if (slot >= n_e) continue;
      long base = (long)(row0 + row) * ND + cb + wc;
#pragma unroll
      for (int n = 0; n < 4; n++){
        float v = acc[m][n][j];
        if (GELU) v = gelu_t(v);
        Cg[base + n * 16 + fr] = f2bf(v);
      }
    }
  }
}

// ---------------- combine: out[t] = g0*y0 + g1*y1 ----------------
__global__ __launch_bounds__(256) void combine_kernel(const u16* __restrict__ ypair,
                                                      const int4* __restrict__ meta,
                                                      const float2* __restrict__ gates,
                                                      const int* __restrict__ offs,
                                                      float* __restrict__ out){
  int t = blockIdx.x;
  int c = threadIdx.x;
  int4 m = meta[t];
  float2 g = gates[t];
  long p0 = (long)(offs[m.x] + m.z) * DDIM + c * 4;
  long p1 = (long)(offs[m.y] + m.w) * DDIM + c * 4;
  u16x4 y0 = *(const u16x4*)&ypair[p0];
  u16x4 y1 = *(const u16x4*)&ypair[p1];
  float4 o;
  o.x = g.x * bf2f(y0[0]) + g.y * bf2f(y1[0]);
  o.y = g.x * bf2f(y0[1]) + g.y * bf2f(y1[1]);
  o.z = g.x * bf2f(y0[2]) + g.y * bf2f(y1[2]);
  o.w = g.x * bf2f(y0[3]) + g.y * bf2f(y1[3]);
  *(float4*)&out[(long)t * DDIM + c * 4] = o;
}

// ---------------- load-balance loss ----------------
__global__ void lb_kernel(const float* __restrict__ imp, const int* __restrict__ cnt,
                          float* __restrict__ outp){
  if (threadIdx.x == 0 && blockIdx.x == 0){
    float si = 0.f, sl = 0.f;
    for (int e = 0; e < NEXP; e++){ si += imp[e]; sl += (float)cnt[e]; }
    float lb = 0.f;
    for (int e = 0; e < NEXP; e++)
      lb += (imp[e] / (si + 1e-9f)) * ((float)cnt[e] / (sl + 1e-9f));
    outp[0] = lb * (float)NEXP;
  }
}

extern "C" void kernel_launch(void* const* d_in, const int* in_sizes, int n_in,
                              void* d_out, int out_size, void* d_ws, size_t ws_size,
                              hipStream_t stream){
  const float* x  = (const float*)d_in[0];
  const float* Wr = (const float*)d_in[1];
  const float* W1 = (const float*)d_in[2];
  const float* W2 = (const float*)d_in[3];
  float* out = (float*)d_out;
  char* ws = (char*)d_ws;
  size_t off = 0;
  u16* xb = (u16*)(ws + off);   off += (size_t)NTOK * DDIM * 2;
  u16* wt = (u16*)(ws + off);   off += (size_t)NEXP * DDIM * HDIM * 2;   // reused: W1^T then W2^T
  u16* h  = (u16*)(ws + off);   off += (size_t)HROWS * HDIM * 2;
  u16* yp = (u16*)(ws + off);   off += (size_t)NTOK * 2 * DDIM * 2;
  int* elist    = (int*)(ws + off);    off += (size_t)NEXP * NTOK * 4;
  int4* meta    = (int4*)(ws + off);   off += (size_t)NTOK * 16;
  float2* gts   = (float2*)(ws + off); off += (size_t)NTOK * 8;
  int* selrk    = (int*)(ws + off);    off += (size_t)NTOK * 2 * 4;
  int* bhist    = (int*)(ws + off);    off += (size_t)RBLK * NEXP * 4;
  float* impP   = (float*)(ws + off);  off += (size_t)RBLK * NEXP * 4;
  int* cnt      = (int*)(ws + off);    off += 32;
  float* imp    = (float*)(ws + off);  off += 32;
  int* offs     = (int*)(ws + off);    off += 32;
  if (ws_size < off) return;  // insufficient workspace: fail visibly

  cvtx_kernel<<<4096, 256, 0, stream>>>(x, xb);
  route_kernel<<<RBLK, 1024, 0, stream>>>(x, Wr, meta, gts, selrk, bhist, impP);
  scan_kernel<<<1, 512, 0, stream>>>(bhist, impP, cnt, offs, imp);
  fill_kernel<<<NTOK * 2 / 256, 256, 0, stream>>>(selrk, bhist, elist, meta);
  transpose_cvt<<<dim3(HDIM / 64, DDIM / 64, NEXP), 256, 0, stream>>>(W1, wt, DDIM, HDIM);
  gemm128_kernel<DDIM, HDIM, true, true><<<dim3(HDIM / 128, NTOK / 128, NEXP), 256, 0, stream>>>(
      xb, wt, h, elist, cnt, offs);
  transpose_cvt<<<dim3(DDIM / 64, HDIM / 64, NEXP), 256, 0, stream>>>(W2, wt, HDIM, DDIM);
  gemm128_kernel<HDIM, DDIM, false, false><<<dim3(DDIM / 128, NTOK / 128, NEXP), 256, 0, stream>>>(
      h, wt, yp, elist, cnt, offs);
  combine_kernel<<<NTOK, 256, 0, stream>>>(yp, meta, gts, offs, out);
  lb_kernel<<<1, 64, 0, stream>>>(imp, cnt, out + (size_t)NTOK * DDIM);
}

// Round 8
// 531.637 us; speedup vs baseline: 2.6088x; 1.0199x over previous
//
#include <hip/hip_runtime.h>
#include <hip/hip_bf16.h>
#include <math.h>

#define NTOK 8192      // B*T = 4*2048
#define DDIM 1024
#define HDIM 4096
#define NEXP 8
#define HROWS (NTOK*2 + 256)   // compact pair rows + pad for ragged tile overread
#define RBLK 512               // route blocks (16 tokens each)

typedef unsigned int u32;
typedef unsigned short u16;
typedef __bf16 bf16x8 __attribute__((ext_vector_type(8)));
typedef float f32x4 __attribute__((ext_vector_type(4)));
typedef u16 u16x8 __attribute__((ext_vector_type(8)));
typedef u16 u16x4 __attribute__((ext_vector_type(4)));

__device__ __forceinline__ u16 f2bf(float f){
  u32 u = __builtin_bit_cast(u32, f);
  u32 r = (u + 0x7FFFu + ((u >> 16) & 1u)) >> 16;   // RNE
  return (u16)r;
}
__device__ __forceinline__ float bf2f(u16 b){
  u32 u = ((u32)b) << 16;
  return __builtin_bit_cast(float, u);
}
__device__ __forceinline__ void gl_lds16(const void* g, void* l){
  __builtin_amdgcn_global_load_lds(
      (const __attribute__((address_space(1))) u32*)g,
      (__attribute__((address_space(3))) u32*)l, 16, 0, 0);
}
// tanh-form gelu (max |err| vs exact erf-gelu ~1e-3, far inside tolerance)
__device__ __forceinline__ float gelu_t(float v){
  float u = v * (0.7978845608f + 0.0356774081f * v * v);
  float e = __expf(2.0f * u);
  float t = 1.0f - 2.0f / (e + 1.0f);    // tanh(u)
  return 0.5f * v * (1.0f + t);
}

// ------------- transpose+convert: in [R][C] fp32 -> out [C][R] bf16, per expert -------------
// vectorized: float4 loads (16B/lane), u16x4 stores (8B/lane)
__global__ __launch_bounds__(256) void transpose_cvt(const float* __restrict__ in,
                                                     u16* __restrict__ out,
                                                     int R, int C){
  int e = blockIdx.z;
  const float* pin = in + (long)e * R * C;
  u16* pout = out + (long)e * R * C;
  __shared__ u16 tile[64][65];
  int c0 = blockIdx.x * 64, r0 = blockIdx.y * 64;
  int tid = threadIdx.x;
#pragma unroll
  for (int j = 0; j < 4; j++){
    int idx = tid + 256 * j;              // 0..1023 = 64 rows x 16 float4
    int r = idx >> 4, c4 = (idx & 15) << 2;
    float4 v = *(const float4*)(pin + (long)(r0 + r) * C + c0 + c4);
    tile[r][c4]     = f2bf(v.x);
    tile[r][c4 + 1] = f2bf(v.y);
    tile[r][c4 + 2] = f2bf(v.z);
    tile[r][c4 + 3] = f2bf(v.w);
  }
  __syncthreads();
#pragma unroll
  for (int j = 0; j < 4; j++){
    int idx = tid + 256 * j;
    int orow = idx >> 4, c4 = (idx & 15) << 2;
    u16x4 o;
    o[0] = tile[c4][orow];     o[1] = tile[c4 + 1][orow];
    o[2] = tile[c4 + 2][orow]; o[3] = tile[c4 + 3][orow];
    *(u16x4*)(pout + (long)(c0 + orow) * R + r0 + c4) = o;
  }
}

// ---------------- routing phase 1: 1 wave per token; also converts x -> bf16 ----------------
__global__ __launch_bounds__(1024) void route_kernel(const float* __restrict__ x,
                                                     const float* __restrict__ Wr,
                                                     u16* __restrict__ xb,
                                                     int4* __restrict__ meta,
                                                     float2* __restrict__ gates,
                                                     int* __restrict__ selrk,
                                                     int* __restrict__ blockhist,
                                                     float* __restrict__ impPart){
  const int wid = threadIdx.x >> 6;       // 0..15 (token within block)
  const int lane = threadIdx.x & 63;
  const int t = blockIdx.x * 16 + wid;
  const float* xr = x + (long)t * DDIM;
  u16* xbr = xb + (long)t * DDIM;
  float acc[NEXP] = {};
  for (int d0 = lane * 4; d0 < DDIM; d0 += 256){
    float4 xv = *(const float4*)(xr + d0);
    u16x4 xo;
    xo[0] = f2bf(xv.x); xo[1] = f2bf(xv.y); xo[2] = f2bf(xv.z); xo[3] = f2bf(xv.w);
    *(u16x4*)(xbr + d0) = xo;
    const float* w = Wr + d0 * NEXP;
#pragma unroll
    for (int q = 0; q < 4; q++){
      float xq = ((const float*)&xv)[q];
      float4 w0 = *(const float4*)(w + q * NEXP);
      float4 w1 = *(const float4*)(w + q * NEXP + 4);
      acc[0] += xq * w0.x; acc[1] += xq * w0.y; acc[2] += xq * w0.z; acc[3] += xq * w0.w;
      acc[4] += xq * w1.x; acc[5] += xq * w1.y; acc[6] += xq * w1.z; acc[7] += xq * w1.w;
    }
  }
#pragma unroll
  for (int e = 0; e < NEXP; e++){
#pragma unroll
    for (int off = 32; off; off >>= 1) acc[e] += __shfl_xor(acc[e], off, 64);
  }
  __shared__ int sel_s[32];
  __shared__ float p_s[16][NEXP];
  if (lane == 0){
    float mx = acc[0];
#pragma unroll
    for (int e = 1; e < NEXP; e++) mx = fmaxf(mx, acc[e]);
    float p[NEXP]; float s = 0.f;
#pragma unroll
    for (int e = 0; e < NEXP; e++){ p[e] = expf(acc[e] - mx); s += p[e]; }
    float inv = 1.f / s;
#pragma unroll
    for (int e = 0; e < NEXP; e++){ p[e] *= inv; p_s[wid][e] = p[e]; }
    int i0 = 0; float v0 = p[0];
#pragma unroll
    for (int e = 1; e < NEXP; e++) if (p[e] > v0){ v0 = p[e]; i0 = e; }
    int i1 = -1; float v1 = -1.f;
#pragma unroll
    for (int e = 0; e < NEXP; e++) if (e != i0 && p[e] > v1){ v1 = p[e]; i1 = e; }
    float gs = v0 + v1 + 1e-9f;
    meta[t] = make_int4(i0, i1, 0, 0);
    gates[t] = make_float2(v0 / gs, v1 / gs);
    sel_s[wid * 2] = i0;
    sel_s[wid * 2 + 1] = i1;
  }
  __syncthreads();
  const int tid = threadIdx.x;
  if (tid < 32){
    int e = sel_s[tid];
    int r = 0;
    for (int m = 0; m < tid; m++) r += (sel_s[m] == e) ? 1 : 0;
    selrk[blockIdx.x * 32 + tid] = (r << 3) | e;
  }
  if (tid < NEXP){
    int hcount = 0;
#pragma unroll
    for (int m = 0; m < 32; m++) hcount += (sel_s[m] == tid) ? 1 : 0;
    blockhist[blockIdx.x * NEXP + tid] = hcount;
    float s = 0.f;
#pragma unroll
    for (int w = 0; w < 16; w++) s += p_s[w][tid];
    impPart[blockIdx.x * NEXP + tid] = s;
  }
}

// ---------------- routing phase 2: exclusive scan of block histograms ----------------
__global__ __launch_bounds__(512) void scan_kernel(int* __restrict__ blockhist,
                                                   const float* __restrict__ impPart,
                                                   int* __restrict__ cnt,
                                                   int* __restrict__ offs,
                                                   float* __restrict__ imp){
  const int e = threadIdx.x >> 6;     // expert 0..7
  const int lane = threadIdx.x & 63;
  const int base = lane * 8;          // 8 blocks per lane, 512 total
  int v[8]; int s = 0;
#pragma unroll
  for (int i = 0; i < 8; i++){
    int tmp = blockhist[(base + i) * NEXP + e];
    v[i] = s; s += tmp;
  }
  int inc = s;
#pragma unroll
  for (int off = 1; off < 64; off <<= 1){
    int o = __shfl_up(inc, off, 64);
    if (lane >= off) inc += o;
  }
  int excl = inc - s;
#pragma unroll
  for (int i = 0; i < 8; i++) blockhist[(base + i) * NEXP + e] = v[i] + excl;
  int tot = __shfl(inc, 63, 64);
  float fs = 0.f;
#pragma unroll
  for (int i = 0; i < 8; i++) fs += impPart[(base + i) * NEXP + e];
#pragma unroll
  for (int off = 32; off; off >>= 1) fs += __shfl_xor(fs, off, 64);
  __shared__ int cnt_s[NEXP];
  if (lane == 0){ cnt_s[e] = tot; cnt[e] = tot; imp[e] = fs; }
  __syncthreads();
  if (threadIdx.x == 0){
    int o = 0;
    for (int q = 0; q < NEXP; q++){ offs[q] = o; o += cnt_s[q]; }
  }
}

// ---------------- routing phase 3: write compact expert lists + slots ----------------
__global__ __launch_bounds__(256) void fill_kernel(const int* __restrict__ selrk,
                                                   const int* __restrict__ blockhist,
                                                   int* __restrict__ elist,
                                                   int4* __restrict__ meta){
  int m = blockIdx.x * 256 + threadIdx.x;   // assignment index, 0..2*NTOK-1
  int t = m >> 1, c = m & 1, b = m >> 5;
  int pk = selrk[m];
  int e = pk & 7, r = pk >> 3;
  int gslot = blockhist[b * NEXP + e] + r;
  elist[e * NTOK + gslot] = t;
  ((int*)meta)[t * 4 + 2 + c] = gslot;
}

// ---- 128x128 GEMM, BK=64, single-buffer LDS, T2 swizzle, hoisted LDS addressing ----
// Flat grid, XCD-chunked: e = bid & 7 (expert pinned to XCD), db-inner within expert.
template<int KD, int ND, bool GATHER, bool GELU>
__global__ __launch_bounds__(256) void gemm128_kernel(const u16* __restrict__ Ag,
                                                      const u16* __restrict__ Bg,
                                                      u16* __restrict__ Cg,
                                                      const int* __restrict__ elist,
                                                      const int* __restrict__ cnt,
                                                      const int* __restrict__ offs){
  const int NDB = ND / 128;
  const int bid = blockIdx.x;
  const int e  = bid & 7;          // consecutive bids round-robin XCDs -> expert e lives on XCD e
  const int le = bid >> 3;
  const int db = le % NDB;         // db-inner: consecutive same-XCD blocks share the A-tile
  const int tt = le / NDB;
  const int n_e = cnt[e];
  if (tt * 128 >= n_e) return;
  const int cb = db * 128;
  __shared__ __align__(16) u16 As[128 * 64];
  __shared__ __align__(16) u16 Bs[128 * 64];
  const int tid = threadIdx.x;
  const int csrc = (((tid & 7) ^ ((tid >> 3) & 7)) << 3);   // swizzled global source chunk
  const int clin = (tid & 7) << 3;                          // linear LDS dest chunk
  const int row0 = offs[e] + tt * 128;
  const long bbase = ((long)e * ND + cb) * KD;
  long agb[4], bgb[4]; int lrow[4];
#pragma unroll
  for (int q = 0; q < 4; q++){
    int row = q * 32 + (tid >> 3);
    int arow;
    if (GATHER){
      int slot = tt * 128 + row;
      if (slot >= n_e) slot = n_e - 1;
      arow = elist[e * NTOK + slot];
    } else {
      arow = row0 + row;
    }
    lrow[q] = row;
    agb[q] = (long)arow * KD + csrc;
    bgb[q] = bbase + (long)row * KD + csrc;
  }
  const int wid = tid >> 6, lane = tid & 63;
  const int wr = (wid >> 1) * 64, wc = (wid & 1) * 64;
  const int fr = lane & 15, fq = lane >> 4;
  // K-invariant swizzled fragment base pointers (r&7 == fr&7 for all fragment rows)
  const int sw0 = (fq ^ (fr & 7)) << 3;          // kk = 0 chunk byte offset (elems)
  const int sw1 = ((4 + fq) ^ (fr & 7)) << 3;    // kk = 1
  const u16* aP0 = &As[(wr + fr) * 64 + sw0];
  const u16* aP1 = &As[(wr + fr) * 64 + sw1];
  const u16* bP0 = &Bs[(wc + fr) * 64 + sw0];
  const u16* bP1 = &Bs[(wc + fr) * 64 + sw1];
  f32x4 acc[4][4] = {};
  for (int kb = 0; kb < KD; kb += 64){
    __syncthreads();
#pragma unroll
    for (int q = 0; q < 4; q++){
      gl_lds16(Ag + agb[q] + kb, &As[lrow[q] * 64 + clin]);
      gl_lds16(Bg + bgb[q] + kb, &Bs[lrow[q] * 64 + clin]);
    }
    __syncthreads();
    {
      bf16x8 af[4], bfr[4];
#pragma unroll
      for (int m = 0; m < 4; m++) af[m] = *(const bf16x8*)(aP0 + m * 1024);
#pragma unroll
      for (int n = 0; n < 4; n++) bfr[n] = *(const bf16x8*)(bP0 + n * 1024);
#pragma unroll
      for (int m = 0; m < 4; m++)
#pragma unroll
        for (int n = 0; n < 4; n++)
          acc[m][n] = __builtin_amdgcn_mfma_f32_16x16x32_bf16(af[m], bfr[n], acc[m][n], 0, 0, 0);
    }
    {
      bf16x8 af[4], bfr[4];
#pragma unroll
      for (int m = 0; m < 4; m++) af[m] = *(const bf16x8*)(aP1 + m * 1024);
#pragma unroll
      for (int n = 0; n < 4; n++) bfr[n] = *(const bf16x8*)(bP1 + n * 1024);
#pragma unroll
      for (int m = 0; m < 4; m++)
#pragma unroll
        for (int n = 0; n < 4; n++)
          acc[m][n] = __builtin_amdgcn_mfma_f32_16x16x32_bf16(af[m], bfr[n], acc[m][n], 0, 0, 0);
    }
  }
#pragma unroll
  for (int m = 0; m < 4; m++){
#pragma unroll
    for (int j = 0; j < 4; j++){
      int row = wr + m * 16 + fq * 4 + j;
      int slot = tt * 128 + row;
      if (slot >= n_e) continue;
      long base = (long)(row0 + row) * ND + cb + wc;
#pragma unroll
      for (int n = 0; n < 4; n++){
        float v = acc[m][n][j];
        if (GELU) v = gelu_t(v);
        Cg[base + n * 16 + fr] = f2bf(v);
      }
    }
  }
}

// ---------------- combine: out[t] = g0*y0 + g1*y1 ----------------
__global__ __launch_bounds__(256) void combine_kernel(const u16* __restrict__ ypair,
                                                      const int4* __restrict__ meta,
                                                      const float2* __restrict__ gates,
                                                      const int* __restrict__ offs,
                                                      float* __restrict__ out){
  int t = blockIdx.x;
  int c = threadIdx.x;
  int4 m = meta[t];
  float2 g = gates[t];
  long p0 = (long)(offs[m.x] + m.z) * DDIM + c * 4;
  long p1 = (long)(offs[m.y] + m.w) * DDIM + c * 4;
  u16x4 y0 = *(const u16x4*)&ypair[p0];
  u16x4 y1 = *(const u16x4*)&ypair[p1];
  float4 o;
  o.x = g.x * bf2f(y0[0]) + g.y * bf2f(y1[0]);
  o.y = g.x * bf2f(y0[1]) + g.y * bf2f(y1[1]);
  o.z = g.x * bf2f(y0[2]) + g.y * bf2f(y1[2]);
  o.w = g.x * bf2f(y0[3]) + g.y * bf2f(y1[3]);
  *(float4*)&out[(long)t * DDIM + c * 4] = o;
}

// ---------------- load-balance loss ----------------
__global__ void lb_kernel(const float* __restrict__ imp, const int* __restrict__ cnt,
                          float* __restrict__ outp){
  if (threadIdx.x == 0 && blockIdx.x == 0){
    float si = 0.f, sl = 0.f;
    for (int e = 0; e < NEXP; e++){ si += imp[e]; sl += (float)cnt[e]; }
    float lb = 0.f;
    for (int e = 0; e < NEXP; e++)
      lb += (imp[e] / (si + 1e-9f)) * ((float)cnt[e] / (sl + 1e-9f));
    outp[0] = lb * (float)NEXP;
  }
}

extern "C" void kernel_launch(void* const* d_in, const int* in_sizes, int n_in,
                              void* d_out, int out_size, void* d_ws, size_t ws_size,
                              hipStream_t stream){
  const float* x  = (const float*)d_in[0];
  const float* Wr = (const float*)d_in[1];
  const float* W1 = (const float*)d_in[2];
  const float* W2 = (const float*)d_in[3];
  float* out = (float*)d_out;
  char* ws = (char*)d_ws;
  size_t off = 0;
  u16* xb = (u16*)(ws + off);   off += (size_t)NTOK * DDIM * 2;
  u16* wt = (u16*)(ws + off);   off += (size_t)NEXP * DDIM * HDIM * 2;   // reused: W1^T then W2^T
  u16* h  = (u16*)(ws + off);   off += (size_t)HROWS * HDIM * 2;
  u16* yp = (u16*)(ws + off);   off += (size_t)NTOK * 2 * DDIM * 2;
  int* elist    = (int*)(ws + off);    off += (size_t)NEXP * NTOK * 4;
  int4* meta    = (int4*)(ws + off);   off += (size_t)NTOK * 16;
  float2* gts   = (float2*)(ws + off); off += (size_t)NTOK * 8;
  int* selrk    = (int*)(ws + off);    off += (size_t)NTOK * 2 * 4;
  int* bhist    = (int*)(ws + off);    off += (size_t)RBLK * NEXP * 4;
  float* impP   = (float*)(ws + off);  off += (size_t)RBLK * NEXP * 4;
  int* cnt      = (int*)(ws + off);    off += 32;
  float* imp    = (float*)(ws + off);  off += 32;
  int* offs     = (int*)(ws + off);    off += 32;
  if (ws_size < off) return;  // insufficient workspace: fail visibly

  route_kernel<<<RBLK, 1024, 0, stream>>>(x, Wr, xb, meta, gts, selrk, bhist, impP);
  scan_kernel<<<1, 512, 0, stream>>>(bhist, impP, cnt, offs, imp);
  fill_kernel<<<NTOK * 2 / 256, 256, 0, stream>>>(selrk, bhist, elist, meta);
  transpose_cvt<<<dim3(HDIM / 64, DDIM / 64, NEXP), 256, 0, stream>>>(W1, wt, DDIM, HDIM);
  gemm128_kernel<DDIM, HDIM, true, true><<<NEXP * (NTOK / 128) * (HDIM / 128), 256, 0, stream>>>(
      xb, wt, h, elist, cnt, offs);
  transpose_cvt<<<dim3(DDIM / 64, HDIM / 64, NEXP), 256, 0, stream>>>(W2, wt, HDIM, DDIM);
  gemm128_kernel<HDIM, DDIM, false, false><<<NEXP * (NTOK / 128) * (DDIM / 128), 256, 0, stream>>>(
      h, wt, yp, elist, cnt, offs);
  combine_kernel<<<NTOK, 256, 0, stream>>>(yp, meta, gts, offs, out);
  lb_kernel<<<1, 64, 0, stream>>>(imp, cnt, out + (size_t)NTOK * DDIM);
}

// Round 9
// 502.948 us; speedup vs baseline: 2.7576x; 1.0570x over previous
//
#include <hip/hip_runtime.h>
#include <hip/hip_bf16.h>
#include <math.h>

#define NTOK 8192      // B*T = 4*2048
#define DDIM 1024
#define HDIM 4096
#define NEXP 8
#define HROWS (NTOK*2 + 256)   // compact pair rows + pad for ragged tile overread
#define RBLK 512               // route blocks (16 tokens each)

typedef unsigned int u32;
typedef unsigned short u16;
typedef __bf16 bf16x8 __attribute__((ext_vector_type(8)));
typedef float f32x4 __attribute__((ext_vector_type(4)));
typedef u32 u32x4 __attribute__((ext_vector_type(4)));
typedef u16 u16x8 __attribute__((ext_vector_type(8)));
typedef u16 u16x4 __attribute__((ext_vector_type(4)));

__device__ __forceinline__ u16 f2bf(float f){
  u32 u = __builtin_bit_cast(u32, f);
  u32 r = (u + 0x7FFFu + ((u >> 16) & 1u)) >> 16;   // RNE
  return (u16)r;
}
__device__ __forceinline__ float bf2f(u16 b){
  u32 u = ((u32)b) << 16;
  return __builtin_bit_cast(float, u);
}
__device__ __forceinline__ void gl_lds16(const void* g, void* l){
  __builtin_amdgcn_global_load_lds(
      (const __attribute__((address_space(1))) u32*)g,
      (__attribute__((address_space(3))) u32*)l, 16, 0, 0);
}
// tanh-form gelu (max |err| vs exact erf-gelu ~1e-3, far inside tolerance)
__device__ __forceinline__ float gelu_t(float v){
  float u = v * (0.7978845608f + 0.0356774081f * v * v);
  float e = __expf(2.0f * u);
  float t = 1.0f - 2.0f / (e + 1.0f);    // tanh(u)
  return 0.5f * v * (1.0f + t);
}

// ------------- transpose+convert: in [R][C] fp32 -> out [C][R] bf16, per expert -------------
__global__ __launch_bounds__(256) void transpose_cvt(const float* __restrict__ in,
                                                     u16* __restrict__ out,
                                                     int R, int C){
  int e = blockIdx.z;
  const float* pin = in + (long)e * R * C;
  u16* pout = out + (long)e * R * C;
  __shared__ u16 tile[64][65];
  int c0 = blockIdx.x * 64, r0 = blockIdx.y * 64;
  int tid = threadIdx.x;
#pragma unroll
  for (int j = 0; j < 4; j++){
    int idx = tid + 256 * j;              // 0..1023 = 64 rows x 16 float4
    int r = idx >> 4, c4 = (idx & 15) << 2;
    float4 v = *(const float4*)(pin + (long)(r0 + r) * C + c0 + c4);
    tile[r][c4]     = f2bf(v.x);
    tile[r][c4 + 1] = f2bf(v.y);
    tile[r][c4 + 2] = f2bf(v.z);
    tile[r][c4 + 3] = f2bf(v.w);
  }
  __syncthreads();
#pragma unroll
  for (int j = 0; j < 4; j++){
    int idx = tid + 256 * j;
    int orow = idx >> 4, c4 = (idx & 15) << 2;
    u16x4 o;
    o[0] = tile[c4][orow];     o[1] = tile[c4 + 1][orow];
    o[2] = tile[c4 + 2][orow]; o[3] = tile[c4 + 3][orow];
    *(u16x4*)(pout + (long)(c0 + orow) * R + r0 + c4) = o;
  }
}

// ---------------- routing phase 1: 1 wave per token; also converts x -> bf16 ----------------
__global__ __launch_bounds__(1024) void route_kernel(const float* __restrict__ x,
                                                     const float* __restrict__ Wr,
                                                     u16* __restrict__ xb,
                                                     int4* __restrict__ meta,
                                                     float2* __restrict__ gates,
                                                     int* __restrict__ selrk,
                                                     int* __restrict__ blockhist,
                                                     float* __restrict__ impPart){
  const int wid = threadIdx.x >> 6;       // 0..15 (token within block)
  const int lane = threadIdx.x & 63;
  const int t = blockIdx.x * 16 + wid;
  const float* xr = x + (long)t * DDIM;
  u16* xbr = xb + (long)t * DDIM;
  float acc[NEXP] = {};
  for (int d0 = lane * 4; d0 < DDIM; d0 += 256){
    float4 xv = *(const float4*)(xr + d0);
    u16x4 xo;
    xo[0] = f2bf(xv.x); xo[1] = f2bf(xv.y); xo[2] = f2bf(xv.z); xo[3] = f2bf(xv.w);
    *(u16x4*)(xbr + d0) = xo;
    const float* w = Wr + d0 * NEXP;
#pragma unroll
    for (int q = 0; q < 4; q++){
      float xq = ((const float*)&xv)[q];
      float4 w0 = *(const float4*)(w + q * NEXP);
      float4 w1 = *(const float4*)(w + q * NEXP + 4);
      acc[0] += xq * w0.x; acc[1] += xq * w0.y; acc[2] += xq * w0.z; acc[3] += xq * w0.w;
      acc[4] += xq * w1.x; acc[5] += xq * w1.y; acc[6] += xq * w1.z; acc[7] += xq * w1.w;
    }
  }
#pragma unroll
  for (int e = 0; e < NEXP; e++){
#pragma unroll
    for (int off = 32; off; off >>= 1) acc[e] += __shfl_xor(acc[e], off, 64);
  }
  __shared__ int sel_s[32];
  __shared__ float p_s[16][NEXP];
  if (lane == 0){
    float mx = acc[0];
#pragma unroll
    for (int e = 1; e < NEXP; e++) mx = fmaxf(mx, acc[e]);
    float p[NEXP]; float s = 0.f;
#pragma unroll
    for (int e = 0; e < NEXP; e++){ p[e] = expf(acc[e] - mx); s += p[e]; }
    float inv = 1.f / s;
#pragma unroll
    for (int e = 0; e < NEXP; e++){ p[e] *= inv; p_s[wid][e] = p[e]; }
    int i0 = 0; float v0 = p[0];
#pragma unroll
    for (int e = 1; e < NEXP; e++) if (p[e] > v0){ v0 = p[e]; i0 = e; }
    int i1 = -1; float v1 = -1.f;
#pragma unroll
    for (int e = 0; e < NEXP; e++) if (e != i0 && p[e] > v1){ v1 = p[e]; i1 = e; }
    float gs = v0 + v1 + 1e-9f;
    meta[t] = make_int4(i0, i1, 0, 0);
    gates[t] = make_float2(v0 / gs, v1 / gs);
    sel_s[wid * 2] = i0;
    sel_s[wid * 2 + 1] = i1;
  }
  __syncthreads();
  const int tid = threadIdx.x;
  if (tid < 32){
    int e = sel_s[tid];
    int r = 0;
    for (int m = 0; m < tid; m++) r += (sel_s[m] == e) ? 1 : 0;
    selrk[blockIdx.x * 32 + tid] = (r << 3) | e;
  }
  if (tid < NEXP){
    int hcount = 0;
#pragma unroll
    for (int m = 0; m < 32; m++) hcount += (sel_s[m] == tid) ? 1 : 0;
    blockhist[blockIdx.x * NEXP + tid] = hcount;
    float s = 0.f;
#pragma unroll
    for (int w = 0; w < 16; w++) s += p_s[w][tid];
    impPart[blockIdx.x * NEXP + tid] = s;
  }
}

// ---------------- routing phase 2: exclusive scan of block histograms ----------------
__global__ __launch_bounds__(512) void scan_kernel(int* __restrict__ blockhist,
                                                   const float* __restrict__ impPart,
                                                   int* __restrict__ cnt,
                                                   int* __restrict__ offs,
                                                   float* __restrict__ imp){
  const int e = threadIdx.x >> 6;     // expert 0..7
  const int lane = threadIdx.x & 63;
  const int base = lane * 8;          // 8 blocks per lane, 512 total
  int v[8]; int s = 0;
#pragma unroll
  for (int i = 0; i < 8; i++){
    int tmp = blockhist[(base + i) * NEXP + e];
    v[i] = s; s += tmp;
  }
  int inc = s;
#pragma unroll
  for (int off = 1; off < 64; off <<= 1){
    int o = __shfl_up(inc, off, 64);
    if (lane >= off) inc += o;
  }
  int excl = inc - s;
#pragma unroll
  for (int i = 0; i < 8; i++) blockhist[(base + i) * NEXP + e] = v[i] + excl;
  int tot = __shfl(inc, 63, 64);
  float fs = 0.f;
#pragma unroll
  for (int i = 0; i < 8; i++) fs += impPart[(base + i) * NEXP + e];
#pragma unroll
  for (int off = 32; off; off >>= 1) fs += __shfl_xor(fs, off, 64);
  __shared__ int cnt_s[NEXP];
  if (lane == 0){ cnt_s[e] = tot; cnt[e] = tot; imp[e] = fs; }
  __syncthreads();
  if (threadIdx.x == 0){
    int o = 0;
    for (int q = 0; q < NEXP; q++){ offs[q] = o; o += cnt_s[q]; }
  }
}

// ---------------- routing phase 3: write compact expert lists + slots ----------------
__global__ __launch_bounds__(256) void fill_kernel(const int* __restrict__ selrk,
                                                   const int* __restrict__ blockhist,
                                                   int* __restrict__ elist,
                                                   int4* __restrict__ meta){
  int m = blockIdx.x * 256 + threadIdx.x;   // assignment index, 0..2*NTOK-1
  int t = m >> 1, c = m & 1, b = m >> 5;
  int pk = selrk[m];
  int e = pk & 7, r = pk >> 3;
  int gslot = blockhist[b * NEXP + e] + r;
  elist[e * NTOK + gslot] = t;
  ((int*)meta)[t * 4 + 2 + c] = gslot;
}

// ---- 128x256 GEMM, BK=32, TRIPLE-buffered LDS, counted vmcnt(6), asm ds_read ----
// Pipeline: stage k+2 while computing k; tile k+1 stays in flight across the barrier.
// LDS swizzle involution (64B rows): chunk q <-> q ^ (R&3) ^ ((R>>2)&3).
template<int KD, int ND, bool GATHER, bool GELU>
__global__ __launch_bounds__(256, 2) void gemm_tb(const u16* __restrict__ Ag,
                                                  const u16* __restrict__ Bg,
                                                  u16* __restrict__ Cg,
                                                  const int* __restrict__ elist,
                                                  const int* __restrict__ cnt,
                                                  const int* __restrict__ offs){
  const int NDB = ND / 256;
  const int bid = blockIdx.x;
  const int e  = bid & 7;          // expert pinned to XCD
  const int le = bid >> 3;
  const int db = le % NDB;         // db-inner: same-XCD neighbors share the A-tile
  const int tt = le / NDB;
  const int n_e = cnt[e];
  if (tt * 128 >= n_e) return;
  const int cb = db * 256;
  __shared__ __align__(16) u16 As[3][128 * 32];   // 3 x 8 KiB
  __shared__ __align__(16) u16 Bs[3][256 * 32];   // 3 x 16 KiB
  const int tid = threadIdx.x;
  // staging: thread t covers row (call*64 + (t>>2)), source chunk pre-swizzled
  const int sch = (((tid & 3) ^ ((tid >> 2) & 3) ^ ((tid >> 4) & 3)) << 3);
  const int row0 = offs[e] + tt * 128;
  long agb[2];
#pragma unroll
  for (int i = 0; i < 2; i++){
    int row = i * 64 + (tid >> 2);
    int arow;
    if (GATHER){
      int slot = tt * 128 + row;
      if (slot >= n_e) slot = n_e - 1;
      arow = elist[e * NTOK + slot];
    } else {
      arow = row0 + row;
    }
    agb[i] = (long)arow * KD + sch;
  }
  const long bbase = ((long)e * ND + cb) * KD;
  long bgb[4];
#pragma unroll
  for (int j = 0; j < 4; j++)
    bgb[j] = bbase + (long)(j * 64 + (tid >> 2)) * KD + sch;
  const int ldst = tid * 8;   // linear LDS dest (elements): wave-uniform base + lane*16B

  const int lane = tid & 63;
  const int w = tid >> 6;      // 4 waves split the 256 N-cols
  const int wc = w * 64;
  const int fr = lane & 15, fq = lane >> 4;
  // K-invariant swizzled read bases (byte addresses)
  const int swz = ((fq ^ (fr & 3) ^ ((fr >> 2) & 3)) << 4);
  const u32 aB0 = (u32)(uintptr_t)&As[0][0] + (u32)(fr * 64 + swz);
  const u32 bB0 = (u32)(uintptr_t)&Bs[0][0] + (u32)((wc + fr) * 64 + swz);

  f32x4 acc[8][4] = {};
  const int NK = KD / 32;

#define STG(cbuf, kel) \
    gl_lds16(Ag + agb[0] + (kel), &As[cbuf][0 * 2048 + ldst]); \
    gl_lds16(Ag + agb[1] + (kel), &As[cbuf][1 * 2048 + ldst]); \
    gl_lds16(Bg + bgb[0] + (kel), &Bs[cbuf][0 * 2048 + ldst]); \
    gl_lds16(Bg + bgb[1] + (kel), &Bs[cbuf][1 * 2048 + ldst]); \
    gl_lds16(Bg + bgb[2] + (kel), &Bs[cbuf][2 * 2048 + ldst]); \
    gl_lds16(Bg + bgb[3] + (kel), &Bs[cbuf][3 * 2048 + ldst]);

  STG(0, 0)
  STG(1, 32)
  asm volatile("s_waitcnt vmcnt(6)" ::: "memory");   // tile 0 landed, tile 1 in flight
  __builtin_amdgcn_s_barrier();

  int c = 0;
  for (int k = 0; k < NK; ++k){
    if (k + 2 < NK){
      int cn = c + 2; if (cn >= 3) cn -= 3;
      STG(cn, (k + 2) * 32)
    }
    const u32 aA = aB0 + (u32)(c * 8192);
    const u32 bA = bB0 + (u32)(c * 16384);
    u32x4 a[8], b[4];
    asm volatile("ds_read_b128 %0, %1"             : "=v"(a[0]) : "v"(aA));
    asm volatile("ds_read_b128 %0, %1 offset:1024" : "=v"(a[1]) : "v"(aA));
    asm volatile("ds_read_b128 %0, %1 offset:2048" : "=v"(a[2]) : "v"(aA));
    asm volatile("ds_read_b128 %0, %1 offset:3072" : "=v"(a[3]) : "v"(aA));
    asm volatile("ds_read_b128 %0, %1 offset:4096" : "=v"(a[4]) : "v"(aA));
    asm volatile("ds_read_b128 %0, %1 offset:5120" : "=v"(a[5]) : "v"(aA));
    asm volatile("ds_read_b128 %0, %1 offset:6144" : "=v"(a[6]) : "v"(aA));
    asm volatile("ds_read_b128 %0, %1 offset:7168" : "=v"(a[7]) : "v"(aA));
    asm volatile("ds_read_b128 %0, %1"             : "=v"(b[0]) : "v"(bA));
    asm volatile("ds_read_b128 %0, %1 offset:1024" : "=v"(b[1]) : "v"(bA));
    asm volatile("ds_read_b128 %0, %1 offset:2048" : "=v"(b[2]) : "v"(bA));
    asm volatile("ds_read_b128 %0, %1 offset:3072" : "=v"(b[3]) : "v"(bA));
    asm volatile("s_waitcnt lgkmcnt(0)" ::: "memory");
    __builtin_amdgcn_sched_barrier(0);               // rule #18: pin MFMA after the wait
#pragma unroll
    for (int m = 0; m < 8; m++)
#pragma unroll
      for (int n = 0; n < 4; n++)
        acc[m][n] = __builtin_amdgcn_mfma_f32_16x16x32_bf16(
            __builtin_bit_cast(bf16x8, a[m]), __builtin_bit_cast(bf16x8, b[n]),
            acc[m][n], 0, 0, 0);
    if (k + 2 < NK){
      asm volatile("s_waitcnt vmcnt(6)" ::: "memory");   // tile k+1 done; k+2 stays in flight
    } else if (k + 1 < NK){
      asm volatile("s_waitcnt vmcnt(0)" ::: "memory");   // tail: drain last tile
    }
    if (k + 1 < NK) __builtin_amdgcn_s_barrier();
    c += 1; if (c >= 3) c -= 3;
  }
#undef STG

  // epilogue: C/D layout col=lane&15, row=(lane>>4)*4+reg
#pragma unroll
  for (int m = 0; m < 8; m++){
#pragma unroll
    for (int j = 0; j < 4; j++){
      int row = m * 16 + fq * 4 + j;
      int slot = tt * 128 + row;
      if (slot >= n_e) continue;
      long base = (long)(row0 + row) * ND + cb + wc;
#pragma unroll
      for (int n = 0; n < 4; n++){
        float v = acc[m][n][j];
        if (GELU) v = gelu_t(v);
        Cg[base + n * 16 + fr] = f2bf(v);
      }
    }
  }
}

// ---------------- combine: out[t] = g0*y0 + g1*y1 ----------------
__global__ __launch_bounds__(256) void combine_kernel(const u16* __restrict__ ypair,
                                                      const int4* __restrict__ meta,
                                                      const float2* __restrict__ gates,
                                                      const int* __restrict__ offs,
                                                      float* __restrict__ out){
  int t = blockIdx.x;
  int c = threadIdx.x;
  int4 m = meta[t];
  float2 g = gates[t];
  long p0 = (long)(offs[m.x] + m.z) * DDIM + c * 4;
  long p1 = (long)(offs[m.y] + m.w) * DDIM + c * 4;
  u16x4 y0 = *(const u16x4*)&ypair[p0];
  u16x4 y1 = *(const u16x4*)&ypair[p1];
  float4 o;
  o.x = g.x * bf2f(y0[0]) + g.y * bf2f(y1[0]);
  o.y = g.x * bf2f(y0[1]) + g.y * bf2f(y1[1]);
  o.z = g.x * bf2f(y0[2]) + g.y * bf2f(y1[2]);
  o.w = g.x * bf2f(y0[3]) + g.y * bf2f(y1[3]);
  *(float4*)&out[(long)t * DDIM + c * 4] = o;
}

// ---------------- load-balance loss ----------------
__global__ void lb_kernel(const float* __restrict__ imp, const int* __restrict__ cnt,
                          float* __restrict__ outp){
  if (threadIdx.x == 0 && blockIdx.x == 0){
    float si = 0.f, sl = 0.f;
    for (int e = 0; e < NEXP; e++){ si += imp[e]; sl += (float)cnt[e]; }
    float lb = 0.f;
    for (int e = 0; e < NEXP; e++)
      lb += (imp[e] / (si + 1e-9f)) * ((float)cnt[e] / (sl + 1e-9f));
    outp[0] = lb * (float)NEXP;
  }
}

extern "C" void kernel_launch(void* const* d_in, const int* in_sizes, int n_in,
                              void* d_out, int out_size, void* d_ws, size_t ws_size,
                              hipStream_t stream){
  const float* x  = (const float*)d_in[0];
  const float* Wr = (const float*)d_in[1];
  const float* W1 = (const float*)d_in[2];
  const float* W2 = (const float*)d_in[3];
  float* out = (float*)d_out;
  char* ws = (char*)d_ws;
  size_t off = 0;
  u16* xb = (u16*)(ws + off);   off += (size_t)NTOK * DDIM * 2;
  u16* wt = (u16*)(ws + off);   off += (size_t)NEXP * DDIM * HDIM * 2;   // reused: W1^T then W2^T
  u16* h  = (u16*)(ws + off);   off += (size_t)HROWS * HDIM * 2;
  u16* yp = (u16*)(ws + off);   off += (size_t)NTOK * 2 * DDIM * 2;
  int* elist    = (int*)(ws + off);    off += (size_t)NEXP * NTOK * 4;
  int4* meta    = (int4*)(ws + off);   off += (size_t)NTOK * 16;
  float2* gts   = (float2*)(ws + off); off += (size_t)NTOK * 8;
  int* selrk    = (int*)(ws + off);    off += (size_t)NTOK * 2 * 4;
  int* bhist    = (int*)(ws + off);    off += (size_t)RBLK * NEXP * 4;
  float* impP   = (float*)(ws + off);  off += (size_t)RBLK * NEXP * 4;
  int* cnt      = (int*)(ws + off);    off += 32;
  float* imp    = (float*)(ws + off);  off += 32;
  int* offs     = (int*)(ws + off);    off += 32;
  if (ws_size < off) return;  // insufficient workspace: fail visibly

  route_kernel<<<RBLK, 1024, 0, stream>>>(x, Wr, xb, meta, gts, selrk, bhist, impP);
  scan_kernel<<<1, 512, 0, stream>>>(bhist, impP, cnt, offs, imp);
  fill_kernel<<<NTOK * 2 / 256, 256, 0, stream>>>(selrk, bhist, elist, meta);
  transpose_cvt<<<dim3(HDIM / 64, DDIM / 64, NEXP), 256, 0, stream>>>(W1, wt, DDIM, HDIM);
  gemm_tb<DDIM, HDIM, true, true><<<NEXP * (NTOK / 128) * (HDIM / 256), 256, 0, stream>>>(
      xb, wt, h, elist, cnt, offs);
  transpose_cvt<<<dim3(DDIM / 64, HDIM / 64, NEXP), 256, 0, stream>>>(W2, wt, HDIM, DDIM);
  gemm_tb<HDIM, DDIM, false, false><<<NEXP * (NTOK / 128) * (DDIM / 256), 256, 0, stream>>>(
      h, wt, yp, elist, cnt, offs);
  combine_kernel<<<NTOK, 256, 0, stream>>>(yp, meta, gts, offs, out);
  lb_kernel<<<1, 64, 0, stream>>>(imp, cnt, out + (size_t)NTOK * DDIM);
}